// Round 1
// baseline (458.800 us; speedup 1.0000x reference)
//
#include <hip/hip_runtime.h>
#include <hip/hip_bf16.h>
#include <math.h>

#define S 2048
#define D 512
#define H 8
#define KH 2
#define DH 64
#define G 4
#define CBS 32
#define NSEL 8
#define WIN 128
#define NC 64
#define CDIM 2048

typedef __attribute__((ext_vector_type(8))) short bf16x8_t;
typedef __attribute__((ext_vector_type(4))) float f32x4_t;

static __device__ __forceinline__ unsigned short f2bf(float f) {
    union { float f; unsigned int u; } v; v.f = f;
    unsigned int r = (v.u + 0x7FFFu + ((v.u >> 16) & 1u)) >> 16;
    return (unsigned short)r;
}
static __device__ __forceinline__ float bf2f(unsigned short h) {
    union { unsigned int u; float f; } v; v.u = ((unsigned int)h) << 16;
    return v.f;
}

// ---------------- conversions ----------------
__global__ void k_f2bf4(const float4* __restrict__ in, uint2* __restrict__ out, int n4) {
    int i = blockIdx.x * 256 + threadIdx.x;
    if (i >= n4) return;
    float4 v = in[i];
    uint2 r;
    r.x = (unsigned)f2bf(v.x) | ((unsigned)f2bf(v.y) << 16);
    r.y = (unsigned)f2bf(v.z) | ((unsigned)f2bf(v.w) << 16);
    out[i] = r;
}

// ---------------- RMSNorm -> x bf16 ----------------
__global__ __launch_bounds__(256) void k_rmsnorm(const float* __restrict__ inp,
                                                 const float* __restrict__ w,
                                                 unsigned short* __restrict__ xbf) {
    int s = blockIdx.x; int t = threadIdx.x;
    const float* row = inp + (size_t)s * D;
    float a = row[t], b = row[t + 256];
    float ss = a * a + b * b;
    for (int off = 32; off; off >>= 1) ss += __shfl_xor(ss, off);
    __shared__ float red[4];
    if ((t & 63) == 0) red[t >> 6] = ss;
    __syncthreads();
    float tot = red[0] + red[1] + red[2] + red[3];
    float inv = rsqrtf(tot / (float)D + 1.1920929e-07f);
    xbf[(size_t)s * D + t]       = f2bf(a * inv * w[t]);
    xbf[(size_t)s * D + t + 256] = f2bf(b * inv * w[t + 256]);
}

// ---------------- generic bf16 MFMA GEMM 64x64 tile ----------------
// MODE 0: qkv scatter (fp32 q/k/v).  MODE 1: +bias, relu, bf16 out (hid), W per row-block.
// MODE 2: plain fp32 out.
template<int MODE>
__global__ __launch_bounds__(256) void k_gemm(
    const unsigned short* __restrict__ A,
    const unsigned short* __restrict__ B0,
    const unsigned short* __restrict__ B1,
    const float* __restrict__ bias0, const float* __restrict__ bias1,
    int M, int N, int K,
    float* __restrict__ q, float* __restrict__ kk, float* __restrict__ vv,
    unsigned short* __restrict__ hid, float* __restrict__ outC)
{
    __shared__ __align__(16) unsigned short As[64][40];
    __shared__ __align__(16) unsigned short Bs[64][40];
    int t = threadIdx.x;
    int m0 = blockIdx.y * 64, n0 = blockIdx.x * 64;
    const unsigned short* W = B0;
    const float* bias = bias0;
    if (MODE == 1 && blockIdx.y >= 2) { W = B1; bias = bias1; }
    int wave = t >> 6, lane = t & 63;
    int mh = wave & 1, nh = wave >> 1;
    f32x4_t acc[2][2] = {};
    int ar = t >> 2, ac = (t & 3) * 8;
    int bk = t >> 3, bn = (t & 7) * 8;
    int arow_l = lane & 15, kcol = (lane >> 4) * 8;
    for (int k0 = 0; k0 < K; k0 += 32) {
        __syncthreads();
        *(uint4*)&As[ar][ac] = *(const uint4*)&A[(size_t)(m0 + ar) * K + k0 + ac];
        uint4 bv = *(const uint4*)&W[(size_t)(k0 + bk) * N + n0 + bn];
        const unsigned short* bp = (const unsigned short*)&bv;
        #pragma unroll
        for (int j = 0; j < 8; ++j) Bs[bn + j][bk] = bp[j];
        __syncthreads();
        bf16x8_t a0 = *(const bf16x8_t*)&As[mh * 32 + arow_l][kcol];
        bf16x8_t a1 = *(const bf16x8_t*)&As[mh * 32 + 16 + arow_l][kcol];
        bf16x8_t b0v = *(const bf16x8_t*)&Bs[nh * 32 + arow_l][kcol];
        bf16x8_t b1v = *(const bf16x8_t*)&Bs[nh * 32 + 16 + arow_l][kcol];
        acc[0][0] = __builtin_amdgcn_mfma_f32_16x16x32_bf16(a0, b0v, acc[0][0], 0, 0, 0);
        acc[0][1] = __builtin_amdgcn_mfma_f32_16x16x32_bf16(a0, b1v, acc[0][1], 0, 0, 0);
        acc[1][0] = __builtin_amdgcn_mfma_f32_16x16x32_bf16(a1, b0v, acc[1][0], 0, 0, 0);
        acc[1][1] = __builtin_amdgcn_mfma_f32_16x16x32_bf16(a1, b1v, acc[1][1], 0, 0, 0);
    }
    #pragma unroll
    for (int mi = 0; mi < 2; ++mi)
    #pragma unroll
    for (int ni = 0; ni < 2; ++ni)
    #pragma unroll
    for (int r = 0; r < 4; ++r) {
        int gm = m0 + mh * 32 + mi * 16 + (lane >> 4) * 4 + r;
        int gn = n0 + nh * 32 + ni * 16 + (lane & 15);
        float val = acc[mi][ni][r];
        if (MODE == 0) {
            if (gn < 512)      q [((gn >> 6) * S + gm) * DH + (gn & 63)] = val;
            else if (gn < 640) kk[(((gn - 512) >> 6) * S + gm) * DH + ((gn - 512) & 63)] = val;
            else               vv[(((gn - 640) >> 6) * S + gm) * DH + ((gn - 640) & 63)] = val;
        } else if (MODE == 1) {
            float h = val + bias[gn]; if (h < 0.f) h = 0.f;
            hid[(size_t)gm * N + gn] = f2bf(h);
        } else {
            outC[(size_t)gm * N + gn] = val;
        }
    }
}

// ---------------- kb/vb builder (k/v + positional, flattened, bf16) ----------------
__global__ void k_build_kbvb(const float* __restrict__ kbuf, const float* __restrict__ vbuf,
                             const float* __restrict__ k_pos, const float* __restrict__ v_pos,
                             unsigned short* __restrict__ kbvb) {
    int idx = blockIdx.x * 256 + threadIdx.x;   // 256*2048
    int r = idx >> 11, c = idx & 2047;
    int tt = c >> 6, dh = c & 63;
    int path = r >> 7, kh = (r >> 6) & 1, nc = r & 63;
    const float* src = path ? vbuf : kbuf;
    const float* pos = path ? v_pos : k_pos;
    float val = src[((kh * S) + nc * 32 + tt) * DH + dh] + pos[(kh * CBS + tt) * DH + dh];
    kbvb[idx] = f2bf(val);
}

// ---------------- mem_kv -> ck/cv row 0 ----------------
__global__ void k_mem_init(const float* __restrict__ mem_kv, float* __restrict__ ck, float* __restrict__ cv) {
    int t = threadIdx.x;
    int path = t >> 7, kh = (t >> 6) & 1, d = t & 63;
    float* dst = path ? cv : ck;
    dst[kh * 65 * 64 + d] = mem_kv[path * (KH * DH) + kh * DH + d];
}

// ---------------- MLP second layer (skinny, fp32) ----------------
__global__ __launch_bounds__(256) void k_mlp2(const unsigned short* __restrict__ hid,
    const float* __restrict__ kc_w2, const float* __restrict__ kc_b2,
    const float* __restrict__ vc_w2, const float* __restrict__ vc_b2,
    float* __restrict__ ck, float* __restrict__ cv)
{
    int r = blockIdx.x, t = threadIdx.x;
    int path = r >> 7, kh = (r >> 6) & 1, nc = r & 63;
    const float* Wm = path ? vc_w2 : kc_w2;
    const float* b2 = path ? vc_b2 : kc_b2;
    int col = t & 63, part = t >> 6;
    const unsigned short* hrow = hid + (size_t)r * CDIM;
    float acc = 0.f;
    for (int k = part * 512; k < part * 512 + 512; ++k)
        acc += bf2f(hrow[k]) * Wm[k * 64 + col];
    __shared__ float red[4][64];
    red[part][col] = acc;
    __syncthreads();
    if (t < 64) {
        float sum = red[0][t] + red[1][t] + red[2][t] + red[3][t] + b2[t];
        float* dst = path ? cv : ck;
        dst[(kh * 65 + 1 + nc) * 64 + t] = sum;
    }
}

// ---------------- RoPE ----------------
__global__ void k_rope_table(float* __restrict__ ct, float* __restrict__ st) {
    int idx = blockIdx.x * 256 + threadIdx.x;   // 2048*32
    int s = idx >> 5, p = idx & 31;
    float inv = powf(10000.0f, -(float)p / 32.0f);
    float fr = (float)s * inv;
    ct[idx] = cosf(fr); st[idx] = sinf(fr);
}

__global__ void k_rope(const float* __restrict__ src, float* __restrict__ dst,
                       const float* __restrict__ ct, const float* __restrict__ st, int nrows) {
    int idx = blockIdx.x * 256 + threadIdx.x;
    if (idx >= nrows * 32) return;
    int row = idx >> 5, p = idx & 31;
    int s = row & (S - 1);
    float x0 = src[row * 64 + 2 * p], x1 = src[row * 64 + 2 * p + 1];
    float c = ct[s * 32 + p], sn = st[s * 32 + p];
    dst[row * 64 + 2 * p]     = x0 * c - x1 * sn;
    dst[row * 64 + 2 * p + 1] = x1 * c + x0 * sn;
}

// ---------------- compressed attention + importance + top-8 ----------------
__global__ __launch_bounds__(256) void k_cattn(
    const float* __restrict__ q, const float* __restrict__ ck, const float* __restrict__ cv,
    float* __restrict__ c_out, int* __restrict__ sel)
{
    int kh = blockIdx.x >> 8, sc = blockIdx.x & 255;   // grid = 2*256
    int s_base = sc * 8;
    __shared__ float ckT[64][65];   // [d][j]
    __shared__ float cvL[64][66];   // [j][d]
    __shared__ float qL[4][64];
    __shared__ float simL[4][64];
    int t = threadIdx.x;
    for (int idx = t; idx < 4096; idx += 256) {
        int j = idx >> 6, d = idx & 63;
        ckT[d][j] = ck[(kh * 65 + j) * 64 + d];
        cvL[j][d] = cv[(kh * 65 + j) * 64 + d];
    }
    int g = t >> 6, lane = t & 63;
    for (int si = 0; si < 8; ++si) {
        int s = s_base + si;
        __syncthreads();
        qL[g][lane] = q[((kh * G + g) * S + s) * DH + lane];
        __syncthreads();
        int j = lane;
        bool valid = (j == 0) || (s >= j * 32);
        float sim = 0.f;
        #pragma unroll 8
        for (int d = 0; d < 64; ++d) sim += qL[g][d] * ckT[d][j];
        sim *= 0.125f;
        float simm = valid ? sim : -INFINITY;
        simL[g][j] = simm;
        float m = simm;
        for (int off = 32; off; off >>= 1) m = fmaxf(m, __shfl_xor(m, off));
        float p = valid ? __expf(simm - m) : 0.f;
        float den = p;
        for (int off = 32; off; off >>= 1) den += __shfl_xor(den, off);
        float pn = p / den;
        float acc = 0.f;
        #pragma unroll 8
        for (int jj = 0; jj < 64; ++jj)
            acc += __shfl(pn, jj) * cvL[jj][lane];
        c_out[((kh * G + g) * S + s) * DH + lane] = acc;
        __syncthreads();
        if (g == 0) {
            int l = lane;
            float lv = -INFINITY;
            if (l < 63 && s >= (l + 1) * 32)
                lv = 0.25f * (simL[0][l + 1] + simL[1][l + 1] + simL[2][l + 1] + simL[3][l + 1]);
            float mm = lv;
            for (int off = 32; off; off >>= 1) mm = fmaxf(mm, __shfl_xor(mm, off));
            mm = fmaxf(mm, -1000.0f);
            float e = (lv == -INFINITY) ? 0.f : __expf(lv - mm);
            float dd = e;
            for (int off = 32; off; off >>= 1) dd += __shfl_xor(dd, off);
            dd += __expf(-1000.0f - mm);
            float val = e / dd;
            float vc = val;
            int base = (kh * S + s) * 9;
            for (int t8 = 0; t8 < 8; ++t8) {
                float bv2 = vc; int bi = l;
                for (int off = 32; off; off >>= 1) {
                    float ov = __shfl_xor(bv2, off); int oi = __shfl_xor(bi, off);
                    if (ov > bv2 || (ov == bv2 && oi < bi)) { bv2 = ov; bi = oi; }
                }
                if (l == 0) sel[base + t8] = (bv2 > 1e-10f) ? bi : -1;
                if (l == bi) vc = -1.f;
            }
            if (l == 0) sel[base + 8] = s >> 5;
        }
    }
}

// ---------------- fine (selected-block) attention ----------------
__global__ __launch_bounds__(256) void k_fattn(
    const float* __restrict__ qr, const float* __restrict__ kr, const float* __restrict__ vv,
    const int* __restrict__ sel, float* __restrict__ f_out)
{
    int kh = blockIdx.x >> 11, s = blockIdx.x & 2047;
    int t = threadIdx.x, g = t >> 6, lane = t & 63;
    __shared__ float KT[64][65];   // [d][j]
    __shared__ float VL[64][66];   // [j][d]
    __shared__ float qL[4][64];
    qL[g][lane] = qr[((kh * G + g) * S + s) * DH + lane];
    int base = (kh * S + s) * 9;
    int own_t = s & 31;
    float m_run = -INFINITY, l_run = 0.f, acc = 0.f;
    for (int c = 0; c < 5; ++c) {
        int bA = sel[base + c * 2];
        int bB = (c < 4) ? sel[base + c * 2 + 1] : -1;
        if (bA < 0 && bB < 0) continue;
        __syncthreads();
        for (int idx = t; idx < 4096; idx += 256) {
            int rl = idx >> 6, d = idx & 63;
            int b = (rl >= 32) ? bB : bA;
            if (b >= 0) {
                int o2 = (kh * S + b * 32 + (rl & 31)) * DH + d;
                KT[d][rl] = kr[o2];
                VL[rl][d] = vv[o2];
            }
        }
        __syncthreads();
        int j = lane;
        int bj = (j >= 32) ? bB : bA;
        bool valid = bj >= 0;
        if (c == 4) valid = valid && (j < 32) && (j <= own_t);
        float sim = -INFINITY;
        if (valid) {
            float sv = 0.f;
            #pragma unroll 8
            for (int d = 0; d < 64; ++d) sv += qL[g][d] * KT[d][j];
            sim = sv * 0.125f;
        }
        float cm = sim;
        for (int off = 32; off; off >>= 1) cm = fmaxf(cm, __shfl_xor(cm, off));
        float nm = fmaxf(m_run, cm);
        float alpha = __expf(m_run - nm);
        float p = valid ? __expf(sim - nm) : 0.f;
        float ps = p;
        for (int off = 32; off; off >>= 1) ps += __shfl_xor(ps, off);
        l_run = l_run * alpha + ps;
        acc *= alpha;
        if (bA >= 0) {
            #pragma unroll 8
            for (int jj = 0; jj < 32; ++jj) acc += __shfl(p, jj) * VL[jj][lane];
        }
        if (bB >= 0) {
            #pragma unroll 8
            for (int jj = 32; jj < 64; ++jj) acc += __shfl(p, jj) * VL[jj][lane];
        }
        m_run = nm;
    }
    f_out[((kh * G + g) * S + s) * DH + lane] = acc / l_run;
}

// ---------------- sliding-window attention ----------------
__global__ __launch_bounds__(256) void k_sattn(
    const float* __restrict__ qr, const float* __restrict__ kr, const float* __restrict__ vv,
    float* __restrict__ s_out)
{
    int kh = blockIdx.x >> 11, s = blockIdx.x & 2047;
    int t = threadIdx.x, g = t >> 6, lane = t & 63;
    __shared__ float KT[64][65];
    __shared__ float VL[64][66];
    __shared__ float qL[4][64];
    qL[g][lane] = qr[((kh * G + g) * S + s) * DH + lane];
    int lo = s - WIN; if (lo < 0) lo = 0;
    float m_run = -INFINITY, l_run = 0.f, acc = 0.f;
    for (int base_k = lo; base_k <= s; base_k += 64) {
        __syncthreads();
        for (int idx = t; idx < 4096; idx += 256) {
            int rl = idx >> 6, d = idx & 63;
            int key = base_k + rl;
            if (key <= s) {
                int o2 = (kh * S + key) * DH + d;
                KT[d][rl] = kr[o2];
                VL[rl][d] = vv[o2];
            } else { KT[d][rl] = 0.f; VL[rl][d] = 0.f; }
        }
        __syncthreads();
        int key = base_k + lane;
        bool valid = key <= s;
        float sim = -INFINITY;
        if (valid) {
            float sv = 0.f;
            #pragma unroll 8
            for (int d = 0; d < 64; ++d) sv += qL[g][d] * KT[d][lane];
            sim = sv * 0.125f;
        }
        float cm = sim;
        for (int off = 32; off; off >>= 1) cm = fmaxf(cm, __shfl_xor(cm, off));
        float nm = fmaxf(m_run, cm);
        float alpha = __expf(m_run - nm);
        float p = valid ? __expf(sim - nm) : 0.f;
        float ps = p;
        for (int off = 32; off; off >>= 1) ps += __shfl_xor(ps, off);
        l_run = l_run * alpha + ps;
        acc *= alpha;
        #pragma unroll 8
        for (int jj = 0; jj < 64; ++jj) acc += __shfl(p, jj) * VL[jj][lane];
        m_run = nm;
    }
    s_out[((kh * G + g) * S + s) * DH + lane] = acc / l_run;
}

// ---------------- gates + combine -> bf16 ----------------
__global__ __launch_bounds__(256) void k_combine(
    const unsigned short* __restrict__ xbf, const float* __restrict__ comb_w, const float* __restrict__ comb_b,
    const float* __restrict__ c_out, const float* __restrict__ f_out, const float* __restrict__ s_out,
    unsigned short* __restrict__ comb)
{
    int s = blockIdx.x, t = threadIdx.x;
    __shared__ float gpart[24][8];
    __shared__ float gates[24];
    if (t < 192) {
        int cc = t >> 3, pt = t & 7;
        float sum = 0.f;
        for (int d = pt * 64; d < pt * 64 + 64; ++d)
            sum += bf2f(xbf[s * D + d]) * comb_w[d * 24 + cc];
        gpart[cc][pt] = sum;
    }
    __syncthreads();
    if (t < 24) {
        float sum = comb_b[t];
        for (int i = 0; i < 8; ++i) sum += gpart[t][i];
        gates[t] = 1.f / (1.f + __expf(-sum));
    }
    __syncthreads();
    for (int o = t; o < 512; o += 256) {
        int h = o >> 6, d = o & 63;
        int idx = (h * S + s) * DH + d;
        float r = gates[h * 3] * c_out[idx] + gates[h * 3 + 1] * f_out[idx] + gates[h * 3 + 2] * s_out[idx];
        comb[s * D + o] = f2bf(r);
    }
}

extern "C" void kernel_launch(void* const* d_in, const int* in_sizes, int n_in,
                              void* d_out, int out_size, void* d_ws, size_t ws_size,
                              hipStream_t stream)
{
    (void)in_sizes; (void)n_in; (void)out_size; (void)ws_size;
    const float* inp    = (const float*)d_in[0];
    const float* norm_w = (const float*)d_in[1];
    const float* w_qkv  = (const float*)d_in[2];
    const float* mem_kv = (const float*)d_in[3];
    const float* k_pos  = (const float*)d_in[4];
    const float* v_pos  = (const float*)d_in[5];
    const float* kc_w1  = (const float*)d_in[6];
    const float* kc_b1  = (const float*)d_in[7];
    const float* kc_w2  = (const float*)d_in[8];
    const float* kc_b2  = (const float*)d_in[9];
    const float* vc_w1  = (const float*)d_in[10];
    const float* vc_b1  = (const float*)d_in[11];
    const float* vc_w2  = (const float*)d_in[12];
    const float* vc_b2  = (const float*)d_in[13];
    const float* comb_w = (const float*)d_in[14];
    const float* comb_b = (const float*)d_in[15];
    const float* out_w  = (const float*)d_in[16];
    float* out = (float*)d_out;

    char* w = (char*)d_ws;
    size_t off = 0;
    auto alloc = [&](size_t bytes) { void* p = w + off; off += (bytes + 255) & ~(size_t)255; return p; };
    unsigned short* xbf   = (unsigned short*)alloc((size_t)S * D * 2);
    unsigned short* wqkvb = (unsigned short*)alloc((size_t)512 * 768 * 2);
    unsigned short* kcw1b = (unsigned short*)alloc((size_t)2048 * 2048 * 2);
    unsigned short* vcw1b = (unsigned short*)alloc((size_t)2048 * 2048 * 2);
    unsigned short* outwb = (unsigned short*)alloc((size_t)512 * 512 * 2);
    unsigned short* kbvb  = (unsigned short*)alloc((size_t)256 * 2048 * 2);
    unsigned short* hid   = (unsigned short*)alloc((size_t)256 * 2048 * 2);
    unsigned short* combb = (unsigned short*)alloc((size_t)S * 512 * 2);
    float* qb   = (float*)alloc((size_t)H * S * DH * 4);
    float* kbuf = (float*)alloc((size_t)KH * S * DH * 4);
    float* vbuf = (float*)alloc((size_t)KH * S * DH * 4);
    float* qrb  = (float*)alloc((size_t)H * S * DH * 4);
    float* krb  = (float*)alloc((size_t)KH * S * DH * 4);
    float* ckb  = (float*)alloc((size_t)KH * 65 * 64 * 4);
    float* cvb  = (float*)alloc((size_t)KH * 65 * 64 * 4);
    float* cob  = (float*)alloc((size_t)H * S * DH * 4);
    float* fob  = (float*)alloc((size_t)H * S * DH * 4);
    float* sob  = (float*)alloc((size_t)H * S * DH * 4);
    float* ctab = (float*)alloc((size_t)S * 32 * 4);
    float* stab = (float*)alloc((size_t)S * 32 * 4);
    int*   selb = (int*)alloc((size_t)KH * S * 9 * 4);

    // weight conversions to bf16
    k_f2bf4<<<(98304 + 255) / 256, 256, 0, stream>>>((const float4*)w_qkv, (uint2*)wqkvb, 98304);
    k_f2bf4<<<(1048576 + 255) / 256, 256, 0, stream>>>((const float4*)kc_w1, (uint2*)kcw1b, 1048576);
    k_f2bf4<<<(1048576 + 255) / 256, 256, 0, stream>>>((const float4*)vc_w1, (uint2*)vcw1b, 1048576);
    k_f2bf4<<<(65536 + 255) / 256, 256, 0, stream>>>((const float4*)out_w, (uint2*)outwb, 65536);

    // RMSNorm
    k_rmsnorm<<<S, 256, 0, stream>>>(inp, norm_w, xbf);

    // QKV projection (scatter to q/k/v fp32)
    k_gemm<0><<<dim3(768 / 64, S / 64), 256, 0, stream>>>(
        xbf, wqkvb, nullptr, nullptr, nullptr, S, 768, 512,
        qb, kbuf, vbuf, nullptr, nullptr);

    // compress MLP layer 1 (fused K+V paths)
    k_build_kbvb<<<(256 * 2048) / 256, 256, 0, stream>>>(kbuf, vbuf, k_pos, v_pos, kbvb);
    k_gemm<1><<<dim3(2048 / 64, 256 / 64), 256, 0, stream>>>(
        kbvb, kcw1b, vcw1b, kc_b1, vc_b1, 256, 2048, 2048,
        nullptr, nullptr, nullptr, hid, nullptr);

    // compress MLP layer 2 + mem row
    k_mem_init<<<1, 256, 0, stream>>>(mem_kv, ckb, cvb);
    k_mlp2<<<256, 256, 0, stream>>>(hid, kc_w2, kc_b2, vc_w2, vc_b2, ckb, cvb);

    // RoPE
    k_rope_table<<<(S * 32) / 256, 256, 0, stream>>>(ctab, stab);
    k_rope<<<(H * S * 32) / 256, 256, 0, stream>>>(qb, qrb, ctab, stab, H * S);
    k_rope<<<(KH * S * 32) / 256, 256, 0, stream>>>(kbuf, krb, ctab, stab, KH * S);

    // compressed attention + importance + top-8 selection
    k_cattn<<<KH * 256, 256, 0, stream>>>(qb, ckb, cvb, cob, selb);

    // fine + sliding attention
    k_fattn<<<KH * S, 256, 0, stream>>>(qrb, krb, vbuf, selb, fob);
    k_sattn<<<KH * S, 256, 0, stream>>>(qrb, krb, vbuf, sob);

    // gated combine + output projection
    k_combine<<<S, 256, 0, stream>>>(xbf, comb_w, comb_b, cob, fob, sob, combb);
    k_gemm<2><<<dim3(512 / 64, S / 64), 256, 0, stream>>>(
        combb, outwb, nullptr, nullptr, nullptr, S, 512, 512,
        nullptr, nullptr, nullptr, nullptr, out);
}

// Round 2
// 372.115 us; speedup vs baseline: 1.2330x; 1.2330x over previous
//
#include <hip/hip_runtime.h>
#include <hip/hip_bf16.h>
#include <math.h>

#define S 2048
#define D 512
#define H 8
#define KH 2
#define DH 64
#define G 4
#define CBS 32
#define NSEL 8
#define WIN 128
#define NC 64
#define CDIM 2048

typedef __attribute__((ext_vector_type(8))) short bf16x8_t;
typedef __attribute__((ext_vector_type(4))) float f32x4_t;

static __device__ __forceinline__ unsigned short f2bf(float f) {
    union { float f; unsigned int u; } v; v.f = f;
    unsigned int r = (v.u + 0x7FFFu + ((v.u >> 16) & 1u)) >> 16;
    return (unsigned short)r;
}
static __device__ __forceinline__ float bf2f(unsigned short h) {
    union { unsigned int u; float f; } v; v.u = ((unsigned int)h) << 16;
    return v.f;
}
static __device__ __forceinline__ float bflo(unsigned int u) {
    union { unsigned int u; float f; } v; v.u = u << 16; return v.f;
}
static __device__ __forceinline__ float bfhi(unsigned int u) {
    union { unsigned int u; float f; } v; v.u = u & 0xffff0000u; return v.f;
}

// ---------------- conversions ----------------
__global__ void k_f2bf4(const float4* __restrict__ in, uint2* __restrict__ out, int n4) {
    int i = blockIdx.x * 256 + threadIdx.x;
    if (i >= n4) return;
    float4 v = in[i];
    uint2 r;
    r.x = (unsigned)f2bf(v.x) | ((unsigned)f2bf(v.y) << 16);
    r.y = (unsigned)f2bf(v.z) | ((unsigned)f2bf(v.w) << 16);
    out[i] = r;
}

// ---------------- RMSNorm -> x bf16 ----------------
__global__ __launch_bounds__(256) void k_rmsnorm(const float* __restrict__ inp,
                                                 const float* __restrict__ w,
                                                 unsigned short* __restrict__ xbf) {
    int s = blockIdx.x; int t = threadIdx.x;
    const float* row = inp + (size_t)s * D;
    float a = row[t], b = row[t + 256];
    float ss = a * a + b * b;
    for (int off = 32; off; off >>= 1) ss += __shfl_xor(ss, off);
    __shared__ float red[4];
    if ((t & 63) == 0) red[t >> 6] = ss;
    __syncthreads();
    float tot = red[0] + red[1] + red[2] + red[3];
    float inv = rsqrtf(tot / (float)D + 1.1920929e-07f);
    xbf[(size_t)s * D + t]       = f2bf(a * inv * w[t]);
    xbf[(size_t)s * D + t + 256] = f2bf(b * inv * w[t + 256]);
}

// ---------------- generic bf16 MFMA GEMM 64x64 tile ----------------
template<int MODE>
__global__ __launch_bounds__(256) void k_gemm(
    const unsigned short* __restrict__ A,
    const unsigned short* __restrict__ B0,
    const unsigned short* __restrict__ B1,
    const float* __restrict__ bias0, const float* __restrict__ bias1,
    int M, int N, int K,
    float* __restrict__ q, float* __restrict__ kk, float* __restrict__ vv,
    unsigned short* __restrict__ hid, float* __restrict__ outC)
{
    __shared__ __align__(16) unsigned short As[64][40];
    __shared__ __align__(16) unsigned short Bs[64][40];
    int t = threadIdx.x;
    int m0 = blockIdx.y * 64, n0 = blockIdx.x * 64;
    const unsigned short* W = B0;
    const float* bias = bias0;
    if (MODE == 1 && blockIdx.y >= 2) { W = B1; bias = bias1; }
    int wave = t >> 6, lane = t & 63;
    int mh = wave & 1, nh = wave >> 1;
    f32x4_t acc[2][2] = {};
    int ar = t >> 2, ac = (t & 3) * 8;
    int bk = t >> 3, bn = (t & 7) * 8;
    int arow_l = lane & 15, kcol = (lane >> 4) * 8;
    for (int k0 = 0; k0 < K; k0 += 32) {
        __syncthreads();
        *(uint4*)&As[ar][ac] = *(const uint4*)&A[(size_t)(m0 + ar) * K + k0 + ac];
        uint4 bv = *(const uint4*)&W[(size_t)(k0 + bk) * N + n0 + bn];
        const unsigned short* bp = (const unsigned short*)&bv;
        #pragma unroll
        for (int j = 0; j < 8; ++j) Bs[bn + j][bk] = bp[j];
        __syncthreads();
        bf16x8_t a0 = *(const bf16x8_t*)&As[mh * 32 + arow_l][kcol];
        bf16x8_t a1 = *(const bf16x8_t*)&As[mh * 32 + 16 + arow_l][kcol];
        bf16x8_t b0v = *(const bf16x8_t*)&Bs[nh * 32 + arow_l][kcol];
        bf16x8_t b1v = *(const bf16x8_t*)&Bs[nh * 32 + 16 + arow_l][kcol];
        acc[0][0] = __builtin_amdgcn_mfma_f32_16x16x32_bf16(a0, b0v, acc[0][0], 0, 0, 0);
        acc[0][1] = __builtin_amdgcn_mfma_f32_16x16x32_bf16(a0, b1v, acc[0][1], 0, 0, 0);
        acc[1][0] = __builtin_amdgcn_mfma_f32_16x16x32_bf16(a1, b0v, acc[1][0], 0, 0, 0);
        acc[1][1] = __builtin_amdgcn_mfma_f32_16x16x32_bf16(a1, b1v, acc[1][1], 0, 0, 0);
    }
    #pragma unroll
    for (int mi = 0; mi < 2; ++mi)
    #pragma unroll
    for (int ni = 0; ni < 2; ++ni)
    #pragma unroll
    for (int r = 0; r < 4; ++r) {
        int gm = m0 + mh * 32 + mi * 16 + (lane >> 4) * 4 + r;
        int gn = n0 + nh * 32 + ni * 16 + (lane & 15);
        float val = acc[mi][ni][r];
        if (MODE == 0) {
            if (gn < 512)      q [((gn >> 6) * S + gm) * DH + (gn & 63)] = val;
            else if (gn < 640) kk[(((gn - 512) >> 6) * S + gm) * DH + ((gn - 512) & 63)] = val;
            else               vv[(((gn - 640) >> 6) * S + gm) * DH + ((gn - 640) & 63)] = val;
        } else if (MODE == 1) {
            float h = val + bias[gn]; if (h < 0.f) h = 0.f;
            hid[(size_t)gm * N + gn] = f2bf(h);
        } else {
            outC[(size_t)gm * N + gn] = val;
        }
    }
}

// ---------------- kb/vb builder ----------------
__global__ void k_build_kbvb(const float* __restrict__ kbuf, const float* __restrict__ vbuf,
                             const float* __restrict__ k_pos, const float* __restrict__ v_pos,
                             unsigned short* __restrict__ kbvb) {
    int idx = blockIdx.x * 256 + threadIdx.x;   // 256*2048
    int r = idx >> 11, c = idx & 2047;
    int tt = c >> 6, dh = c & 63;
    int path = r >> 7, kh = (r >> 6) & 1, nc = r & 63;
    const float* src = path ? vbuf : kbuf;
    const float* pos = path ? v_pos : k_pos;
    float val = src[((kh * S) + nc * 32 + tt) * DH + dh] + pos[(kh * CBS + tt) * DH + dh];
    kbvb[idx] = f2bf(val);
}

// ---------------- mem_kv -> ck/cv row 0 ----------------
__global__ void k_mem_init(const float* __restrict__ mem_kv, float* __restrict__ ck, float* __restrict__ cv) {
    int t = threadIdx.x;
    int path = t >> 7, kh = (t >> 6) & 1, d = t & 63;
    float* dst = path ? cv : ck;
    dst[kh * 65 * 64 + d] = mem_kv[path * (KH * DH) + kh * DH + d];
}

// ---------------- MLP second layer ----------------
__global__ __launch_bounds__(256) void k_mlp2(const unsigned short* __restrict__ hid,
    const float* __restrict__ kc_w2, const float* __restrict__ kc_b2,
    const float* __restrict__ vc_w2, const float* __restrict__ vc_b2,
    float* __restrict__ ck, float* __restrict__ cv)
{
    int r = blockIdx.x, t = threadIdx.x;
    int path = r >> 7, kh = (r >> 6) & 1, nc = r & 63;
    const float* Wm = path ? vc_w2 : kc_w2;
    const float* b2 = path ? vc_b2 : kc_b2;
    int col = t & 63, part = t >> 6;
    const unsigned short* hrow = hid + (size_t)r * CDIM;
    float acc = 0.f;
    for (int k = part * 512; k < part * 512 + 512; ++k)
        acc += bf2f(hrow[k]) * Wm[k * 64 + col];
    __shared__ float red[4][64];
    red[part][col] = acc;
    __syncthreads();
    if (t < 64) {
        float sum = red[0][t] + red[1][t] + red[2][t] + red[3][t] + b2[t];
        float* dst = path ? cv : ck;
        dst[(kh * 65 + 1 + nc) * 64 + t] = sum;
    }
}

// ---------------- RoPE ----------------
__global__ void k_rope_table(float* __restrict__ ct, float* __restrict__ st) {
    int idx = blockIdx.x * 256 + threadIdx.x;   // 2048*32
    int s = idx >> 5, p = idx & 31;
    float inv = powf(10000.0f, -(float)p / 32.0f);
    float fr = (float)s * inv;
    ct[idx] = cosf(fr); st[idx] = sinf(fr);
}

__global__ void k_rope_bf16(const float* __restrict__ src, unsigned short* __restrict__ dst,
                            const float* __restrict__ ct, const float* __restrict__ st, int nrows) {
    int idx = blockIdx.x * 256 + threadIdx.x;
    if (idx >= nrows * 32) return;
    int row = idx >> 5, p = idx & 31;
    int s = row & (S - 1);
    float x0 = src[row * 64 + 2 * p], x1 = src[row * 64 + 2 * p + 1];
    float c = ct[s * 32 + p], sn = st[s * 32 + p];
    dst[row * 64 + 2 * p]     = f2bf(x0 * c - x1 * sn);
    dst[row * 64 + 2 * p + 1] = f2bf(x1 * c + x0 * sn);
}

// ---------------- compressed attention + importance + top-8 ----------------
__global__ __launch_bounds__(256) void k_cattn(
    const float* __restrict__ q, const float* __restrict__ ck, const float* __restrict__ cv,
    float* __restrict__ c_out, int* __restrict__ sel)
{
    int kh = blockIdx.x >> 8, sc = blockIdx.x & 255;   // grid = 2*256
    int s_base = sc * 8;
    __shared__ float ckT[64][65];   // [d][j]
    __shared__ float cvL[64][66];   // [j][d]
    __shared__ float qL[4][64];
    __shared__ float simL[4][64];
    int t = threadIdx.x;
    for (int idx = t; idx < 4096; idx += 256) {
        int j = idx >> 6, d = idx & 63;
        ckT[d][j] = ck[(kh * 65 + j) * 64 + d];
        cvL[j][d] = cv[(kh * 65 + j) * 64 + d];
    }
    int g = t >> 6, lane = t & 63;
    for (int si = 0; si < 8; ++si) {
        int s = s_base + si;
        __syncthreads();
        qL[g][lane] = q[((kh * G + g) * S + s) * DH + lane];
        __syncthreads();
        int j = lane;
        bool valid = (j == 0) || (s >= j * 32);
        float sim = 0.f;
        #pragma unroll 8
        for (int d = 0; d < 64; ++d) sim += qL[g][d] * ckT[d][j];
        sim *= 0.125f;
        float simm = valid ? sim : -INFINITY;
        simL[g][j] = simm;
        float m = simm;
        for (int off = 32; off; off >>= 1) m = fmaxf(m, __shfl_xor(m, off));
        float p = valid ? __expf(simm - m) : 0.f;
        float den = p;
        for (int off = 32; off; off >>= 1) den += __shfl_xor(den, off);
        float pn = p / den;
        float acc = 0.f;
        #pragma unroll 8
        for (int jj = 0; jj < 64; ++jj)
            acc += __shfl(pn, jj) * cvL[jj][lane];
        c_out[((kh * G + g) * S + s) * DH + lane] = acc;
        __syncthreads();
        if (g == 0) {
            int l = lane;
            float lv = -INFINITY;
            if (l < 63 && s >= (l + 1) * 32)
                lv = 0.25f * (simL[0][l + 1] + simL[1][l + 1] + simL[2][l + 1] + simL[3][l + 1]);
            float mm = lv;
            for (int off = 32; off; off >>= 1) mm = fmaxf(mm, __shfl_xor(mm, off));
            mm = fmaxf(mm, -1000.0f);
            float e = (lv == -INFINITY) ? 0.f : __expf(lv - mm);
            float dd = e;
            for (int off = 32; off; off >>= 1) dd += __shfl_xor(dd, off);
            dd += __expf(-1000.0f - mm);
            float val = e / dd;
            float vc = val;
            int base = (kh * S + s) * 9;
            for (int t8 = 0; t8 < 8; ++t8) {
                float bv2 = vc; int bi = l;
                for (int off = 32; off; off >>= 1) {
                    float ov = __shfl_xor(bv2, off); int oi = __shfl_xor(bi, off);
                    if (ov > bv2 || (ov == bv2 && oi < bi)) { bv2 = ov; bi = oi; }
                }
                if (l == 0) sel[base + t8] = (bv2 > 1e-10f) ? bi : -1;
                if (l == bi) vc = -1.f;
            }
            if (l == 0) sel[base + 8] = s >> 5;
        }
    }
}

// ---------------- fine + sliding attention (vectorized bf16 SIMT) ----------------
// FINE=true: selected-block attention; FINE=false: sliding window.
// Block = (kh, s). 4 waves = 4 grouped queries. K staged XOR-swizzled bf16,
// V staged row-major bf16 [64][72]. PV: lane owns 2 dims x one key-half.
template<bool FINE>
__global__ __launch_bounds__(256, 8) void k_swattn(
    const unsigned short* __restrict__ qr16, const unsigned short* __restrict__ kr16,
    const unsigned short* __restrict__ v16, const int* __restrict__ sel,
    float* __restrict__ outp)
{
    int kh = blockIdx.x >> 11, s = blockIdx.x & 2047;
    int t = threadIdx.x, w = t >> 6, lane = t & 63, g = w;
    __shared__ __align__(16) unsigned char KL[64 * 128];   // swizzled [key][grp^(key&7)]
    __shared__ __align__(16) unsigned char VL[64 * 144];   // [key][72 bf16]
    __shared__ unsigned short qL16[4][64];                  // wave-private
    __shared__ float pL[4][64];                             // wave-private

    qL16[g][lane] = qr16[(((size_t)kh * G + g) * S + s) * DH + lane];

    int own_t = s & 31;
    int base = (kh * S + s) * 9;
    float m_run = -INFINITY, l_run = 0.f;
    float acc0 = 0.f, acc1 = 0.f;
    int h = lane >> 5, dhalf = lane & 31;

    int lo = s - WIN; if (lo < 0) lo = 0;
    int nch = FINE ? 5 : ((s - lo) / 64 + 1);

    for (int c = 0; c < nch; ++c) {
        int bA = 0, bB = 0, kb = 0;
        bool vA, vB;
        if (FINE) {
            bA = sel[base + c * 2];
            bB = (c < 4) ? sel[base + c * 2 + 1] : -1;
            if (bA < 0 && bB < 0) continue;   // uniform across block
            vA = bA >= 0; vB = bB >= 0;
        } else {
            kb = lo + c * 64; vA = true; vB = true;
        }
        __syncthreads();
        // ---- stage K (swizzled) and V (row-major), zero-fill invalid ----
        {
            int key = w * 16 + (lane & 15);
            int gkey; bool kv;
            if (FINE) {
                int b = (key < 32) ? bA : bB;
                kv = b >= 0;
                gkey = (b < 0 ? 0 : b) * 32 + (key & 31);
            } else {
                gkey = kb + key;
                kv = gkey <= s;
            }
            const uint4* kp = (const uint4*)&kr16[((size_t)kh * S + gkey) * DH];
            const uint4* vp = (const uint4*)&v16 [((size_t)kh * S + gkey) * DH];
            uint4 z = make_uint4(0, 0, 0, 0);
            #pragma unroll
            for (int i = 0; i < 2; ++i) {
                int grp = (lane >> 4) + 4 * i;
                uint4 kd = kv ? kp[grp] : z;
                uint4 vd = kv ? vp[grp] : z;
                *(uint4*)(KL + key * 128 + 16 * (grp ^ (key & 7))) = kd;
                *(uint4*)(VL + key * 144 + 16 * grp) = vd;
            }
        }
        __syncthreads();
        // ---- QK^T: lane = key j ----
        int j = lane;
        bool valid;
        if (FINE) {
            valid = (j < 32) ? vA : vB;
            if (c == 4) valid = valid && (j < 32) && (j <= own_t);
        } else {
            valid = (kb + j) <= s;
        }
        float sv = 0.f;
        #pragma unroll
        for (int grp = 0; grp < 8; ++grp) {
            uint4 kk = *(const uint4*)(KL + j * 128 + 16 * (grp ^ (j & 7)));
            uint4 qq = *(const uint4*)((const unsigned char*)qL16 + g * 128 + 16 * grp);
            sv += bflo(qq.x) * bflo(kk.x) + bfhi(qq.x) * bfhi(kk.x);
            sv += bflo(qq.y) * bflo(kk.y) + bfhi(qq.y) * bfhi(kk.y);
            sv += bflo(qq.z) * bflo(kk.z) + bfhi(qq.z) * bfhi(kk.z);
            sv += bflo(qq.w) * bflo(kk.w) + bfhi(qq.w) * bfhi(kk.w);
        }
        float sim = valid ? sv * 0.125f : -INFINITY;
        float cm = sim;
        for (int off = 32; off; off >>= 1) cm = fmaxf(cm, __shfl_xor(cm, off));
        float nm = fmaxf(m_run, cm);
        float alpha = __expf(m_run - nm);
        float p = valid ? __expf(sim - nm) : 0.f;
        float ps = p;
        for (int off = 32; off; off >>= 1) ps += __shfl_xor(ps, off);
        l_run = l_run * alpha + ps;
        pL[g][j] = p;                 // wave-private: no barrier needed
        m_run = nm;
        acc0 *= alpha; acc1 *= alpha;
        // ---- PV: lane owns dims (2*dhalf, 2*dhalf+1), key-half h ----
        bool hv = (h == 0) ? vA : vB;
        if (hv) {
            #pragma unroll
            for (int j4 = 0; j4 < 8; ++j4) {
                float4 p4 = *(const float4*)&pL[g][h * 32 + j4 * 4];
                const float* pp = (const float*)&p4;
                #pragma unroll
                for (int qq = 0; qq < 4; ++qq) {
                    unsigned int v2 = *(const unsigned int*)(VL + (h * 32 + j4 * 4 + qq) * 144 + 4 * dhalf);
                    acc0 += pp[qq] * bflo(v2);
                    acc1 += pp[qq] * bfhi(v2);
                }
            }
        }
    }
    acc0 += __shfl_xor(acc0, 32);
    acc1 += __shfl_xor(acc1, 32);
    if (lane < 32) {
        float inv = 1.f / l_run;
        float2 o2 = make_float2(acc0 * inv, acc1 * inv);
        *(float2*)&outp[(((size_t)kh * G + g) * S + s) * DH + 2 * dhalf] = o2;
    }
}

// ---------------- gates + combine -> bf16 ----------------
__global__ __launch_bounds__(256) void k_combine(
    const unsigned short* __restrict__ xbf, const float* __restrict__ comb_w, const float* __restrict__ comb_b,
    const float* __restrict__ c_out, const float* __restrict__ f_out, const float* __restrict__ s_out,
    unsigned short* __restrict__ comb)
{
    int s = blockIdx.x, t = threadIdx.x;
    __shared__ float gpart[24][8];
    __shared__ float gates[24];
    if (t < 192) {
        int cc = t >> 3, pt = t & 7;
        float sum = 0.f;
        for (int d = pt * 64; d < pt * 64 + 64; ++d)
            sum += bf2f(xbf[s * D + d]) * comb_w[d * 24 + cc];
        gpart[cc][pt] = sum;
    }
    __syncthreads();
    if (t < 24) {
        float sum = comb_b[t];
        for (int i = 0; i < 8; ++i) sum += gpart[t][i];
        gates[t] = 1.f / (1.f + __expf(-sum));
    }
    __syncthreads();
    for (int o = t; o < 512; o += 256) {
        int h = o >> 6, d = o & 63;
        int idx = (h * S + s) * DH + d;
        float r = gates[h * 3] * c_out[idx] + gates[h * 3 + 1] * f_out[idx] + gates[h * 3 + 2] * s_out[idx];
        comb[s * D + o] = f2bf(r);
    }
}

extern "C" void kernel_launch(void* const* d_in, const int* in_sizes, int n_in,
                              void* d_out, int out_size, void* d_ws, size_t ws_size,
                              hipStream_t stream)
{
    (void)in_sizes; (void)n_in; (void)out_size; (void)ws_size;
    const float* inp    = (const float*)d_in[0];
    const float* norm_w = (const float*)d_in[1];
    const float* w_qkv  = (const float*)d_in[2];
    const float* mem_kv = (const float*)d_in[3];
    const float* k_pos  = (const float*)d_in[4];
    const float* v_pos  = (const float*)d_in[5];
    const float* kc_w1  = (const float*)d_in[6];
    const float* kc_b1  = (const float*)d_in[7];
    const float* kc_w2  = (const float*)d_in[8];
    const float* kc_b2  = (const float*)d_in[9];
    const float* vc_w1  = (const float*)d_in[10];
    const float* vc_b1  = (const float*)d_in[11];
    const float* vc_w2  = (const float*)d_in[12];
    const float* vc_b2  = (const float*)d_in[13];
    const float* comb_w = (const float*)d_in[14];
    const float* comb_b = (const float*)d_in[15];
    const float* out_w  = (const float*)d_in[16];
    float* out = (float*)d_out;

    char* w = (char*)d_ws;
    size_t off = 0;
    auto alloc = [&](size_t bytes) { void* p = w + off; off += (bytes + 255) & ~(size_t)255; return p; };
    unsigned short* xbf   = (unsigned short*)alloc((size_t)S * D * 2);
    unsigned short* wqkvb = (unsigned short*)alloc((size_t)512 * 768 * 2);
    unsigned short* kcw1b = (unsigned short*)alloc((size_t)2048 * 2048 * 2);
    unsigned short* vcw1b = (unsigned short*)alloc((size_t)2048 * 2048 * 2);
    unsigned short* outwb = (unsigned short*)alloc((size_t)512 * 512 * 2);
    unsigned short* kbvb  = (unsigned short*)alloc((size_t)256 * 2048 * 2);
    unsigned short* hid   = (unsigned short*)alloc((size_t)256 * 2048 * 2);
    unsigned short* combb = (unsigned short*)alloc((size_t)S * 512 * 2);
    unsigned short* qr16  = (unsigned short*)alloc((size_t)H * S * DH * 2);
    unsigned short* kr16  = (unsigned short*)alloc((size_t)KH * S * DH * 2);
    unsigned short* v16   = (unsigned short*)alloc((size_t)KH * S * DH * 2);
    float* qb   = (float*)alloc((size_t)H * S * DH * 4);
    float* kbuf = (float*)alloc((size_t)KH * S * DH * 4);
    float* vbuf = (float*)alloc((size_t)KH * S * DH * 4);
    float* ckb  = (float*)alloc((size_t)KH * 65 * 64 * 4);
    float* cvb  = (float*)alloc((size_t)KH * 65 * 64 * 4);
    float* cob  = (float*)alloc((size_t)H * S * DH * 4);
    float* fob  = (float*)alloc((size_t)H * S * DH * 4);
    float* sob  = (float*)alloc((size_t)H * S * DH * 4);
    float* ctab = (float*)alloc((size_t)S * 32 * 4);
    float* stab = (float*)alloc((size_t)S * 32 * 4);
    int*   selb = (int*)alloc((size_t)KH * S * 9 * 4);

    // weight conversions to bf16
    k_f2bf4<<<(98304 + 255) / 256, 256, 0, stream>>>((const float4*)w_qkv, (uint2*)wqkvb, 98304);
    k_f2bf4<<<(1048576 + 255) / 256, 256, 0, stream>>>((const float4*)kc_w1, (uint2*)kcw1b, 1048576);
    k_f2bf4<<<(1048576 + 255) / 256, 256, 0, stream>>>((const float4*)vc_w1, (uint2*)vcw1b, 1048576);
    k_f2bf4<<<(65536 + 255) / 256, 256, 0, stream>>>((const float4*)out_w, (uint2*)outwb, 65536);

    // RMSNorm
    k_rmsnorm<<<S, 256, 0, stream>>>(inp, norm_w, xbf);

    // QKV projection
    k_gemm<0><<<dim3(768 / 64, S / 64), 256, 0, stream>>>(
        xbf, wqkvb, nullptr, nullptr, nullptr, S, 768, 512,
        qb, kbuf, vbuf, nullptr, nullptr);

    // compress MLP layer 1
    k_build_kbvb<<<(256 * 2048) / 256, 256, 0, stream>>>(kbuf, vbuf, k_pos, v_pos, kbvb);
    k_gemm<1><<<dim3(2048 / 64, 256 / 64), 256, 0, stream>>>(
        kbvb, kcw1b, vcw1b, kc_b1, vc_b1, 256, 2048, 2048,
        nullptr, nullptr, nullptr, hid, nullptr);

    // compress MLP layer 2 + mem row
    k_mem_init<<<1, 256, 0, stream>>>(mem_kv, ckb, cvb);
    k_mlp2<<<256, 256, 0, stream>>>(hid, kc_w2, kc_b2, vc_w2, vc_b2, ckb, cvb);

    // RoPE (bf16 outputs) + v bf16 conversion
    k_rope_table<<<(S * 32) / 256, 256, 0, stream>>>(ctab, stab);
    k_rope_bf16<<<(H * S * 32) / 256, 256, 0, stream>>>(qb, qr16, ctab, stab, H * S);
    k_rope_bf16<<<(KH * S * 32) / 256, 256, 0, stream>>>(kbuf, kr16, ctab, stab, KH * S);
    k_f2bf4<<<(65536 + 255) / 256, 256, 0, stream>>>((const float4*)vbuf, (uint2*)v16, 65536);

    // compressed attention + importance + top-8 selection
    k_cattn<<<KH * 256, 256, 0, stream>>>(qb, ckb, cvb, cob, selb);

    // fine + sliding attention
    k_swattn<true><<<KH * S, 256, 0, stream>>>(qr16, kr16, v16, selb, fob);
    k_swattn<false><<<KH * S, 256, 0, stream>>>(qr16, kr16, v16, selb, sob);

    // gated combine + output projection
    k_combine<<<S, 256, 0, stream>>>(xbf, comb_w, comb_b, cob, fob, sob, combb);
    k_gemm<2><<<dim3(512 / 64, S / 64), 256, 0, stream>>>(
        combb, outwb, nullptr, nullptr, nullptr, S, 512, 512,
        nullptr, nullptr, nullptr, nullptr, out);
}

// Round 3
// 336.013 us; speedup vs baseline: 1.3654x; 1.1074x over previous
//
#include <hip/hip_runtime.h>
#include <hip/hip_bf16.h>
#include <math.h>

#define S 2048
#define D 512
#define H 8
#define KH 2
#define DH 64
#define G 4
#define CBS 32
#define NSEL 8
#define WIN 128
#define NC 64
#define CDIM 2048

typedef __attribute__((ext_vector_type(8))) short bf16x8_t;
typedef __attribute__((ext_vector_type(4))) float f32x4_t;

static __device__ __forceinline__ unsigned short f2bf(float f) {
    union { float f; unsigned int u; } v; v.f = f;
    unsigned int r = (v.u + 0x7FFFu + ((v.u >> 16) & 1u)) >> 16;
    return (unsigned short)r;
}
static __device__ __forceinline__ float bf2f(unsigned short h) {
    union { unsigned int u; float f; } v; v.u = ((unsigned int)h) << 16;
    return v.f;
}
static __device__ __forceinline__ float bflo(unsigned int u) {
    union { unsigned int u; float f; } v; v.u = u << 16; return v.f;
}
static __device__ __forceinline__ float bfhi(unsigned int u) {
    union { unsigned int u; float f; } v; v.u = u & 0xffff0000u; return v.f;
}

// ---------------- conversions ----------------
__global__ void k_f2bf4(const float4* __restrict__ in, uint2* __restrict__ out, int n4) {
    int i = blockIdx.x * 256 + threadIdx.x;
    if (i >= n4) return;
    float4 v = in[i];
    uint2 r;
    r.x = (unsigned)f2bf(v.x) | ((unsigned)f2bf(v.y) << 16);
    r.y = (unsigned)f2bf(v.z) | ((unsigned)f2bf(v.w) << 16);
    out[i] = r;
}

// ---------------- RMSNorm -> x bf16 ----------------
__global__ __launch_bounds__(256) void k_rmsnorm(const float* __restrict__ inp,
                                                 const float* __restrict__ w,
                                                 unsigned short* __restrict__ xbf) {
    int s = blockIdx.x; int t = threadIdx.x;
    const float* row = inp + (size_t)s * D;
    float a = row[t], b = row[t + 256];
    float ss = a * a + b * b;
    for (int off = 32; off; off >>= 1) ss += __shfl_xor(ss, off);
    __shared__ float red[4];
    if ((t & 63) == 0) red[t >> 6] = ss;
    __syncthreads();
    float tot = red[0] + red[1] + red[2] + red[3];
    float inv = rsqrtf(tot / (float)D + 1.1920929e-07f);
    xbf[(size_t)s * D + t]       = f2bf(a * inv * w[t]);
    xbf[(size_t)s * D + t + 256] = f2bf(b * inv * w[t + 256]);
}

// ---------------- generic bf16 MFMA GEMM 64x64 tile ----------------
template<int MODE>
__global__ __launch_bounds__(256) void k_gemm(
    const unsigned short* __restrict__ A,
    const unsigned short* __restrict__ B0,
    const unsigned short* __restrict__ B1,
    const float* __restrict__ bias0, const float* __restrict__ bias1,
    int M, int N, int K,
    float* __restrict__ q, float* __restrict__ kk, float* __restrict__ vv,
    unsigned short* __restrict__ hid, float* __restrict__ outC)
{
    __shared__ __align__(16) unsigned short As[64][40];
    __shared__ __align__(16) unsigned short Bs[64][40];
    int t = threadIdx.x;
    int m0 = blockIdx.y * 64, n0 = blockIdx.x * 64;
    const unsigned short* W = B0;
    const float* bias = bias0;
    if (MODE == 1 && blockIdx.y >= 2) { W = B1; bias = bias1; }
    int wave = t >> 6, lane = t & 63;
    int mh = wave & 1, nh = wave >> 1;
    f32x4_t acc[2][2] = {};
    int ar = t >> 2, ac = (t & 3) * 8;
    int bk = t >> 3, bn = (t & 7) * 8;
    int arow_l = lane & 15, kcol = (lane >> 4) * 8;
    for (int k0 = 0; k0 < K; k0 += 32) {
        __syncthreads();
        *(uint4*)&As[ar][ac] = *(const uint4*)&A[(size_t)(m0 + ar) * K + k0 + ac];
        uint4 bv = *(const uint4*)&W[(size_t)(k0 + bk) * N + n0 + bn];
        const unsigned short* bp = (const unsigned short*)&bv;
        #pragma unroll
        for (int j = 0; j < 8; ++j) Bs[bn + j][bk] = bp[j];
        __syncthreads();
        bf16x8_t a0 = *(const bf16x8_t*)&As[mh * 32 + arow_l][kcol];
        bf16x8_t a1 = *(const bf16x8_t*)&As[mh * 32 + 16 + arow_l][kcol];
        bf16x8_t b0v = *(const bf16x8_t*)&Bs[nh * 32 + arow_l][kcol];
        bf16x8_t b1v = *(const bf16x8_t*)&Bs[nh * 32 + 16 + arow_l][kcol];
        acc[0][0] = __builtin_amdgcn_mfma_f32_16x16x32_bf16(a0, b0v, acc[0][0], 0, 0, 0);
        acc[0][1] = __builtin_amdgcn_mfma_f32_16x16x32_bf16(a0, b1v, acc[0][1], 0, 0, 0);
        acc[1][0] = __builtin_amdgcn_mfma_f32_16x16x32_bf16(a1, b0v, acc[1][0], 0, 0, 0);
        acc[1][1] = __builtin_amdgcn_mfma_f32_16x16x32_bf16(a1, b1v, acc[1][1], 0, 0, 0);
    }
    #pragma unroll
    for (int mi = 0; mi < 2; ++mi)
    #pragma unroll
    for (int ni = 0; ni < 2; ++ni)
    #pragma unroll
    for (int r = 0; r < 4; ++r) {
        int gm = m0 + mh * 32 + mi * 16 + (lane >> 4) * 4 + r;
        int gn = n0 + nh * 32 + ni * 16 + (lane & 15);
        float val = acc[mi][ni][r];
        if (MODE == 0) {
            if (gn < 512)      q [((gn >> 6) * S + gm) * DH + (gn & 63)] = val;
            else if (gn < 640) kk[(((gn - 512) >> 6) * S + gm) * DH + ((gn - 512) & 63)] = val;
            else               vv[(((gn - 640) >> 6) * S + gm) * DH + ((gn - 640) & 63)] = val;
        } else if (MODE == 1) {
            float h = val + bias[gn]; if (h < 0.f) h = 0.f;
            hid[(size_t)gm * N + gn] = f2bf(h);
        } else {
            outC[(size_t)gm * N + gn] = val;
        }
    }
}

// ---------------- kb/vb builder ----------------
__global__ void k_build_kbvb(const float* __restrict__ kbuf, const float* __restrict__ vbuf,
                             const float* __restrict__ k_pos, const float* __restrict__ v_pos,
                             unsigned short* __restrict__ kbvb) {
    int idx = blockIdx.x * 256 + threadIdx.x;   // 256*2048
    int r = idx >> 11, c = idx & 2047;
    int tt = c >> 6, dh = c & 63;
    int path = r >> 7, kh = (r >> 6) & 1, nc = r & 63;
    const float* src = path ? vbuf : kbuf;
    const float* pos = path ? v_pos : k_pos;
    float val = src[((kh * S) + nc * 32 + tt) * DH + dh] + pos[(kh * CBS + tt) * DH + dh];
    kbvb[idx] = f2bf(val);
}

// ---------------- mem_kv -> ck/cv row 0 ----------------
__global__ void k_mem_init(const float* __restrict__ mem_kv, float* __restrict__ ck, float* __restrict__ cv) {
    int t = threadIdx.x;
    int path = t >> 7, kh = (t >> 6) & 1, d = t & 63;
    float* dst = path ? cv : ck;
    dst[kh * 65 * 64 + d] = mem_kv[path * (KH * DH) + kh * DH + d];
}

// ---------------- MLP second layer ----------------
__global__ __launch_bounds__(256) void k_mlp2(const unsigned short* __restrict__ hid,
    const float* __restrict__ kc_w2, const float* __restrict__ kc_b2,
    const float* __restrict__ vc_w2, const float* __restrict__ vc_b2,
    float* __restrict__ ck, float* __restrict__ cv)
{
    int r = blockIdx.x, t = threadIdx.x;
    int path = r >> 7, kh = (r >> 6) & 1, nc = r & 63;
    const float* Wm = path ? vc_w2 : kc_w2;
    const float* b2 = path ? vc_b2 : kc_b2;
    int col = t & 63, part = t >> 6;
    const unsigned short* hrow = hid + (size_t)r * CDIM;
    float acc = 0.f;
    for (int k = part * 512; k < part * 512 + 512; ++k)
        acc += bf2f(hrow[k]) * Wm[k * 64 + col];
    __shared__ float red[4][64];
    red[part][col] = acc;
    __syncthreads();
    if (t < 64) {
        float sum = red[0][t] + red[1][t] + red[2][t] + red[3][t] + b2[t];
        float* dst = path ? cv : ck;
        dst[(kh * 65 + 1 + nc) * 64 + t] = sum;
    }
}

// ---------------- RoPE ----------------
__global__ void k_rope_table(float* __restrict__ ct, float* __restrict__ st) {
    int idx = blockIdx.x * 256 + threadIdx.x;   // 2048*32
    int s = idx >> 5, p = idx & 31;
    float inv = powf(10000.0f, -(float)p / 32.0f);
    float fr = (float)s * inv;
    ct[idx] = cosf(fr); st[idx] = sinf(fr);
}

__global__ void k_rope_bf16(const float* __restrict__ src, unsigned short* __restrict__ dst,
                            const float* __restrict__ ct, const float* __restrict__ st, int nrows) {
    int idx = blockIdx.x * 256 + threadIdx.x;
    if (idx >= nrows * 32) return;
    int row = idx >> 5, p = idx & 31;
    int s = row & (S - 1);
    float x0 = src[row * 64 + 2 * p], x1 = src[row * 64 + 2 * p + 1];
    float c = ct[s * 32 + p], sn = st[s * 32 + p];
    dst[row * 64 + 2 * p]     = f2bf(x0 * c - x1 * sn);
    dst[row * 64 + 2 * p + 1] = f2bf(x1 * c + x0 * sn);
}

// ---------------- compressed attention + importance + top-8 ----------------
__global__ __launch_bounds__(256) void k_cattn(
    const float* __restrict__ q, const float* __restrict__ ck, const float* __restrict__ cv,
    float* __restrict__ c_out, int* __restrict__ sel)
{
    int kh = blockIdx.x >> 8, sc = blockIdx.x & 255;   // grid = 2*256
    int s_base = sc * 8;
    __shared__ float ckT[64][65];   // [d][j]
    __shared__ float cvL[64][66];   // [j][d]
    __shared__ float qL[4][64];
    __shared__ float simL[4][64];
    int t = threadIdx.x;
    for (int idx = t; idx < 4096; idx += 256) {
        int j = idx >> 6, d = idx & 63;
        ckT[d][j] = ck[(kh * 65 + j) * 64 + d];
        cvL[j][d] = cv[(kh * 65 + j) * 64 + d];
    }
    int g = t >> 6, lane = t & 63;
    for (int si = 0; si < 8; ++si) {
        int s = s_base + si;
        __syncthreads();
        qL[g][lane] = q[((kh * G + g) * S + s) * DH + lane];
        __syncthreads();
        int j = lane;
        bool valid = (j == 0) || (s >= j * 32);
        float sim = 0.f;
        #pragma unroll 8
        for (int d = 0; d < 64; ++d) sim += qL[g][d] * ckT[d][j];
        sim *= 0.125f;
        float simm = valid ? sim : -INFINITY;
        simL[g][j] = simm;
        float m = simm;
        for (int off = 32; off; off >>= 1) m = fmaxf(m, __shfl_xor(m, off));
        float p = valid ? __expf(simm - m) : 0.f;
        float den = p;
        for (int off = 32; off; off >>= 1) den += __shfl_xor(den, off);
        float pn = p / den;
        float acc = 0.f;
        #pragma unroll 8
        for (int jj = 0; jj < 64; ++jj)
            acc += __shfl(pn, jj) * cvL[jj][lane];
        c_out[((kh * G + g) * S + s) * DH + lane] = acc;
        __syncthreads();
        if (g == 0) {
            int l = lane;
            float lv = -INFINITY;
            if (l < 63 && s >= (l + 1) * 32)
                lv = 0.25f * (simL[0][l + 1] + simL[1][l + 1] + simL[2][l + 1] + simL[3][l + 1]);
            float mm = lv;
            for (int off = 32; off; off >>= 1) mm = fmaxf(mm, __shfl_xor(mm, off));
            mm = fmaxf(mm, -1000.0f);
            float e = (lv == -INFINITY) ? 0.f : __expf(lv - mm);
            float dd = e;
            for (int off = 32; off; off >>= 1) dd += __shfl_xor(dd, off);
            dd += __expf(-1000.0f - mm);
            float val = e / dd;
            float vc = val;
            int base = (kh * S + s) * 9;
            for (int t8 = 0; t8 < 8; ++t8) {
                float bv2 = vc; int bi = l;
                for (int off = 32; off; off >>= 1) {
                    float ov = __shfl_xor(bv2, off); int oi = __shfl_xor(bi, off);
                    if (ov > bv2 || (ov == bv2 && oi < bi)) { bv2 = ov; bi = oi; }
                }
                if (l == 0) sel[base + t8] = (bv2 > 1e-10f) ? bi : -1;
                if (l == bi) vc = -1.f;
            }
            if (l == 0) sel[base + 8] = s >> 5;
        }
    }
}

// ---------------- fine + sliding attention (vectorized bf16 SIMT) ----------------
// FINE=true: selected-block attention; FINE=false: sliding window.
// Block = (kh, s). 4 waves = 4 grouped queries. K staged XOR-swizzled bf16,
// V staged row-major bf16 [64][72]. PV: lane owns 2 dims x one key-half.
// launch_bounds(256,4): VGPR cap 128 — the (256,8)/32-VGPR variant spilled to
// scratch (133MB FETCH + 188MB WRITE per dispatch, spill-BW-bound).
template<bool FINE>
__global__ __launch_bounds__(256, 4) void k_swattn(
    const unsigned short* __restrict__ qr16, const unsigned short* __restrict__ kr16,
    const unsigned short* __restrict__ v16, const int* __restrict__ sel,
    float* __restrict__ outp)
{
    int kh = blockIdx.x >> 11, s = blockIdx.x & 2047;
    int t = threadIdx.x, w = t >> 6, lane = t & 63, g = w;
    __shared__ __align__(16) unsigned char KL[64 * 128];   // swizzled [key][grp^(key&7)]
    __shared__ __align__(16) unsigned char VL[64 * 144];   // [key][72 bf16]
    __shared__ unsigned short qL16[4][64];                  // wave-private
    __shared__ float pL[4][64];                             // wave-private

    qL16[g][lane] = qr16[(((size_t)kh * G + g) * S + s) * DH + lane];

    int own_t = s & 31;
    int base = (kh * S + s) * 9;
    float m_run = -INFINITY, l_run = 0.f;
    float acc0 = 0.f, acc1 = 0.f;
    int h = lane >> 5, dhalf = lane & 31;

    int lo = s - WIN; if (lo < 0) lo = 0;
    int nch = FINE ? 5 : ((s - lo) / 64 + 1);

    for (int c = 0; c < nch; ++c) {
        int bA = 0, bB = 0, kb = 0;
        bool vA, vB;
        if (FINE) {
            bA = sel[base + c * 2];
            bB = (c < 4) ? sel[base + c * 2 + 1] : -1;
            if (bA < 0 && bB < 0) continue;   // uniform across block
            vA = bA >= 0; vB = bB >= 0;
        } else {
            kb = lo + c * 64; vA = true; vB = true;
        }
        __syncthreads();
        // ---- stage K (swizzled) and V (row-major), zero-fill invalid ----
        {
            int key = w * 16 + (lane & 15);
            int gkey; bool kv;
            if (FINE) {
                int b = (key < 32) ? bA : bB;
                kv = b >= 0;
                gkey = (b < 0 ? 0 : b) * 32 + (key & 31);
            } else {
                gkey = kb + key;
                kv = gkey <= s;
            }
            const uint4* kp = (const uint4*)&kr16[((size_t)kh * S + gkey) * DH];
            const uint4* vp = (const uint4*)&v16 [((size_t)kh * S + gkey) * DH];
            uint4 z = make_uint4(0, 0, 0, 0);
            #pragma unroll
            for (int i = 0; i < 2; ++i) {
                int grp = (lane >> 4) + 4 * i;
                uint4 kd = kv ? kp[grp] : z;
                uint4 vd = kv ? vp[grp] : z;
                *(uint4*)(KL + key * 128 + 16 * (grp ^ (key & 7))) = kd;
                *(uint4*)(VL + key * 144 + 16 * grp) = vd;
            }
        }
        __syncthreads();
        // ---- QK^T: lane = key j ----
        int j = lane;
        bool valid;
        if (FINE) {
            valid = (j < 32) ? vA : vB;
            if (c == 4) valid = valid && (j < 32) && (j <= own_t);
        } else {
            valid = (kb + j) <= s;
        }
        float sv = 0.f;
        #pragma unroll
        for (int grp = 0; grp < 8; ++grp) {
            uint4 kk = *(const uint4*)(KL + j * 128 + 16 * (grp ^ (j & 7)));
            uint4 qq = *(const uint4*)((const unsigned char*)qL16 + g * 128 + 16 * grp);
            sv += bflo(qq.x) * bflo(kk.x) + bfhi(qq.x) * bfhi(kk.x);
            sv += bflo(qq.y) * bflo(kk.y) + bfhi(qq.y) * bfhi(kk.y);
            sv += bflo(qq.z) * bflo(kk.z) + bfhi(qq.z) * bfhi(kk.z);
            sv += bflo(qq.w) * bflo(kk.w) + bfhi(qq.w) * bfhi(kk.w);
        }
        float sim = valid ? sv * 0.125f : -INFINITY;
        float cm = sim;
        for (int off = 32; off; off >>= 1) cm = fmaxf(cm, __shfl_xor(cm, off));
        float nm = fmaxf(m_run, cm);
        float alpha = __expf(m_run - nm);
        float p = valid ? __expf(sim - nm) : 0.f;
        float ps = p;
        for (int off = 32; off; off >>= 1) ps += __shfl_xor(ps, off);
        l_run = l_run * alpha + ps;
        pL[g][j] = p;                 // wave-private: no barrier needed
        m_run = nm;
        acc0 *= alpha; acc1 *= alpha;
        // ---- PV: lane owns dims (2*dhalf, 2*dhalf+1), key-half h ----
        bool hv = (h == 0) ? vA : vB;
        if (hv) {
            #pragma unroll
            for (int j4 = 0; j4 < 8; ++j4) {
                float4 p4 = *(const float4*)&pL[g][h * 32 + j4 * 4];
                const float* pp = (const float*)&p4;
                #pragma unroll
                for (int qq = 0; qq < 4; ++qq) {
                    unsigned int v2 = *(const unsigned int*)(VL + (h * 32 + j4 * 4 + qq) * 144 + 4 * dhalf);
                    acc0 += pp[qq] * bflo(v2);
                    acc1 += pp[qq] * bfhi(v2);
                }
            }
        }
    }
    acc0 += __shfl_xor(acc0, 32);
    acc1 += __shfl_xor(acc1, 32);
    if (lane < 32) {
        float inv = 1.f / l_run;
        float2 o2 = make_float2(acc0 * inv, acc1 * inv);
        *(float2*)&outp[(((size_t)kh * G + g) * S + s) * DH + 2 * dhalf] = o2;
    }
}

// ---------------- gates + combine -> bf16 ----------------
__global__ __launch_bounds__(256) void k_combine(
    const unsigned short* __restrict__ xbf, const float* __restrict__ comb_w, const float* __restrict__ comb_b,
    const float* __restrict__ c_out, const float* __restrict__ f_out, const float* __restrict__ s_out,
    unsigned short* __restrict__ comb)
{
    int s = blockIdx.x, t = threadIdx.x;
    __shared__ float gpart[24][8];
    __shared__ float gates[24];
    if (t < 192) {
        int cc = t >> 3, pt = t & 7;
        float sum = 0.f;
        for (int d = pt * 64; d < pt * 64 + 64; ++d)
            sum += bf2f(xbf[s * D + d]) * comb_w[d * 24 + cc];
        gpart[cc][pt] = sum;
    }
    __syncthreads();
    if (t < 24) {
        float sum = comb_b[t];
        for (int i = 0; i < 8; ++i) sum += gpart[t][i];
        gates[t] = 1.f / (1.f + __expf(-sum));
    }
    __syncthreads();
    for (int o = t; o < 512; o += 256) {
        int h = o >> 6, d = o & 63;
        int idx = (h * S + s) * DH + d;
        float r = gates[h * 3] * c_out[idx] + gates[h * 3 + 1] * f_out[idx] + gates[h * 3 + 2] * s_out[idx];
        comb[s * D + o] = f2bf(r);
    }
}

extern "C" void kernel_launch(void* const* d_in, const int* in_sizes, int n_in,
                              void* d_out, int out_size, void* d_ws, size_t ws_size,
                              hipStream_t stream)
{
    (void)in_sizes; (void)n_in; (void)out_size; (void)ws_size;
    const float* inp    = (const float*)d_in[0];
    const float* norm_w = (const float*)d_in[1];
    const float* w_qkv  = (const float*)d_in[2];
    const float* mem_kv = (const float*)d_in[3];
    const float* k_pos  = (const float*)d_in[4];
    const float* v_pos  = (const float*)d_in[5];
    const float* kc_w1  = (const float*)d_in[6];
    const float* kc_b1  = (const float*)d_in[7];
    const float* kc_w2  = (const float*)d_in[8];
    const float* kc_b2  = (const float*)d_in[9];
    const float* vc_w1  = (const float*)d_in[10];
    const float* vc_b1  = (const float*)d_in[11];
    const float* vc_w2  = (const float*)d_in[12];
    const float* vc_b2  = (const float*)d_in[13];
    const float* comb_w = (const float*)d_in[14];
    const float* comb_b = (const float*)d_in[15];
    const float* out_w  = (const float*)d_in[16];
    float* out = (float*)d_out;

    char* w = (char*)d_ws;
    size_t off = 0;
    auto alloc = [&](size_t bytes) { void* p = w + off; off += (bytes + 255) & ~(size_t)255; return p; };
    unsigned short* xbf   = (unsigned short*)alloc((size_t)S * D * 2);
    unsigned short* wqkvb = (unsigned short*)alloc((size_t)512 * 768 * 2);
    unsigned short* kcw1b = (unsigned short*)alloc((size_t)2048 * 2048 * 2);
    unsigned short* vcw1b = (unsigned short*)alloc((size_t)2048 * 2048 * 2);
    unsigned short* outwb = (unsigned short*)alloc((size_t)512 * 512 * 2);
    unsigned short* kbvb  = (unsigned short*)alloc((size_t)256 * 2048 * 2);
    unsigned short* hid   = (unsigned short*)alloc((size_t)256 * 2048 * 2);
    unsigned short* combb = (unsigned short*)alloc((size_t)S * 512 * 2);
    unsigned short* qr16  = (unsigned short*)alloc((size_t)H * S * DH * 2);
    unsigned short* kr16  = (unsigned short*)alloc((size_t)KH * S * DH * 2);
    unsigned short* v16   = (unsigned short*)alloc((size_t)KH * S * DH * 2);
    float* qb   = (float*)alloc((size_t)H * S * DH * 4);
    float* kbuf = (float*)alloc((size_t)KH * S * DH * 4);
    float* vbuf = (float*)alloc((size_t)KH * S * DH * 4);
    float* ckb  = (float*)alloc((size_t)KH * 65 * 64 * 4);
    float* cvb  = (float*)alloc((size_t)KH * 65 * 64 * 4);
    float* cob  = (float*)alloc((size_t)H * S * DH * 4);
    float* fob  = (float*)alloc((size_t)H * S * DH * 4);
    float* sob  = (float*)alloc((size_t)H * S * DH * 4);
    float* ctab = (float*)alloc((size_t)S * 32 * 4);
    float* stab = (float*)alloc((size_t)S * 32 * 4);
    int*   selb = (int*)alloc((size_t)KH * S * 9 * 4);

    // weight conversions to bf16
    k_f2bf4<<<(98304 + 255) / 256, 256, 0, stream>>>((const float4*)w_qkv, (uint2*)wqkvb, 98304);
    k_f2bf4<<<(1048576 + 255) / 256, 256, 0, stream>>>((const float4*)kc_w1, (uint2*)kcw1b, 1048576);
    k_f2bf4<<<(1048576 + 255) / 256, 256, 0, stream>>>((const float4*)vc_w1, (uint2*)vcw1b, 1048576);
    k_f2bf4<<<(65536 + 255) / 256, 256, 0, stream>>>((const float4*)out_w, (uint2*)outwb, 65536);

    // RMSNorm
    k_rmsnorm<<<S, 256, 0, stream>>>(inp, norm_w, xbf);

    // QKV projection
    k_gemm<0><<<dim3(768 / 64, S / 64), 256, 0, stream>>>(
        xbf, wqkvb, nullptr, nullptr, nullptr, S, 768, 512,
        qb, kbuf, vbuf, nullptr, nullptr);

    // compress MLP layer 1
    k_build_kbvb<<<(256 * 2048) / 256, 256, 0, stream>>>(kbuf, vbuf, k_pos, v_pos, kbvb);
    k_gemm<1><<<dim3(2048 / 64, 256 / 64), 256, 0, stream>>>(
        kbvb, kcw1b, vcw1b, kc_b1, vc_b1, 256, 2048, 2048,
        nullptr, nullptr, nullptr, hid, nullptr);

    // compress MLP layer 2 + mem row
    k_mem_init<<<1, 256, 0, stream>>>(mem_kv, ckb, cvb);
    k_mlp2<<<256, 256, 0, stream>>>(hid, kc_w2, kc_b2, vc_w2, vc_b2, ckb, cvb);

    // RoPE (bf16 outputs) + v bf16 conversion
    k_rope_table<<<(S * 32) / 256, 256, 0, stream>>>(ctab, stab);
    k_rope_bf16<<<(H * S * 32) / 256, 256, 0, stream>>>(qb, qr16, ctab, stab, H * S);
    k_rope_bf16<<<(KH * S * 32) / 256, 256, 0, stream>>>(kbuf, kr16, ctab, stab, KH * S);
    k_f2bf4<<<(65536 + 255) / 256, 256, 0, stream>>>((const float4*)vbuf, (uint2*)v16, 65536);

    // compressed attention + importance + top-8 selection
    k_cattn<<<KH * 256, 256, 0, stream>>>(qb, ckb, cvb, cob, selb);

    // fine + sliding attention
    k_swattn<true><<<KH * S, 256, 0, stream>>>(qr16, kr16, v16, selb, fob);
    k_swattn<false><<<KH * S, 256, 0, stream>>>(qr16, kr16, v16, selb, sob);

    // gated combine + output projection
    k_combine<<<S, 256, 0, stream>>>(xbf, comb_w, comb_b, cob, fob, sob, combb);
    k_gemm<2><<<dim3(512 / 64, S / 64), 256, 0, stream>>>(
        combb, outwb, nullptr, nullptr, nullptr, S, 512, 512,
        nullptr, nullptr, nullptr, nullptr, out);
}

// Round 4
// 302.606 us; speedup vs baseline: 1.5162x; 1.1104x over previous
//
#include <hip/hip_runtime.h>
#include <hip/hip_bf16.h>
#include <math.h>

#define S 2048
#define D 512
#define H 8
#define KH 2
#define DH 64
#define G 4
#define CBS 32
#define NSEL 8
#define WIN 128
#define NC 64
#define CDIM 2048

typedef __attribute__((ext_vector_type(8))) short bf16x8_t;
typedef __attribute__((ext_vector_type(4))) float f32x4_t;

static __device__ __forceinline__ unsigned short f2bf(float f) {
    union { float f; unsigned int u; } v; v.f = f;
    unsigned int r = (v.u + 0x7FFFu + ((v.u >> 16) & 1u)) >> 16;
    return (unsigned short)r;
}
static __device__ __forceinline__ float bf2f(unsigned short h) {
    union { unsigned int u; float f; } v; v.u = ((unsigned int)h) << 16;
    return v.f;
}
static __device__ __forceinline__ float bflo(unsigned int u) {
    union { unsigned int u; float f; } v; v.u = u << 16; return v.f;
}
static __device__ __forceinline__ float bfhi(unsigned int u) {
    union { unsigned int u; float f; } v; v.u = u & 0xffff0000u; return v.f;
}

// ---------------- RMSNorm -> x bf16 ----------------
__global__ __launch_bounds__(256) void k_rmsnorm(const float* __restrict__ inp,
                                                 const float* __restrict__ w,
                                                 unsigned short* __restrict__ xbf) {
    int s = blockIdx.x; int t = threadIdx.x;
    const float* row = inp + (size_t)s * D;
    float a = row[t], b = row[t + 256];
    float ss = a * a + b * b;
    for (int off = 32; off; off >>= 1) ss += __shfl_xor(ss, off);
    __shared__ float red[4];
    if ((t & 63) == 0) red[t >> 6] = ss;
    __syncthreads();
    float tot = red[0] + red[1] + red[2] + red[3];
    float inv = rsqrtf(tot / (float)D + 1.1920929e-07f);
    xbf[(size_t)s * D + t]       = f2bf(a * inv * w[t]);
    xbf[(size_t)s * D + t + 256] = f2bf(b * inv * w[t + 256]);
}

// ---------------- generic bf16 MFMA GEMM 64x64 tile ----------------
// A is bf16; B weights are read as f32 and converted to bf16 during LDS
// staging (saves the separate conversion dispatches + HBM round trip).
// MODE 0: qkv scatter (fp32 q/k/v).  MODE 1: +bias, relu, bf16 out (hid).
// MODE 2: plain fp32 out.
template<int MODE>
__global__ __launch_bounds__(256) void k_gemm(
    const unsigned short* __restrict__ A,
    const float* __restrict__ B0,
    const float* __restrict__ B1,
    const float* __restrict__ bias0, const float* __restrict__ bias1,
    int M, int N, int K,
    float* __restrict__ q, float* __restrict__ kk, float* __restrict__ vv,
    unsigned short* __restrict__ hid, float* __restrict__ outC)
{
    __shared__ __align__(16) unsigned short As[64][40];
    __shared__ __align__(16) unsigned short Bs[64][40];
    int t = threadIdx.x;
    int m0 = blockIdx.y * 64, n0 = blockIdx.x * 64;
    const float* W = B0;
    const float* bias = bias0;
    if (MODE == 1 && blockIdx.y >= 2) { W = B1; bias = bias1; }
    int wave = t >> 6, lane = t & 63;
    int mh = wave & 1, nh = wave >> 1;
    f32x4_t acc[2][2] = {};
    int ar = t >> 2, ac = (t & 3) * 8;
    int bk = t >> 3, bn = (t & 7) * 8;
    int arow_l = lane & 15, kcol = (lane >> 4) * 8;
    for (int k0 = 0; k0 < K; k0 += 32) {
        __syncthreads();
        *(uint4*)&As[ar][ac] = *(const uint4*)&A[(size_t)(m0 + ar) * K + k0 + ac];
        const float4* wrow = (const float4*)&W[(size_t)(k0 + bk) * N + n0 + bn];
        float4 w0 = wrow[0], w1 = wrow[1];
        unsigned short bp[8];
        bp[0] = f2bf(w0.x); bp[1] = f2bf(w0.y); bp[2] = f2bf(w0.z); bp[3] = f2bf(w0.w);
        bp[4] = f2bf(w1.x); bp[5] = f2bf(w1.y); bp[6] = f2bf(w1.z); bp[7] = f2bf(w1.w);
        #pragma unroll
        for (int j = 0; j < 8; ++j) Bs[bn + j][bk] = bp[j];
        __syncthreads();
        bf16x8_t a0 = *(const bf16x8_t*)&As[mh * 32 + arow_l][kcol];
        bf16x8_t a1 = *(const bf16x8_t*)&As[mh * 32 + 16 + arow_l][kcol];
        bf16x8_t b0v = *(const bf16x8_t*)&Bs[nh * 32 + arow_l][kcol];
        bf16x8_t b1v = *(const bf16x8_t*)&Bs[nh * 32 + 16 + arow_l][kcol];
        acc[0][0] = __builtin_amdgcn_mfma_f32_16x16x32_bf16(a0, b0v, acc[0][0], 0, 0, 0);
        acc[0][1] = __builtin_amdgcn_mfma_f32_16x16x32_bf16(a0, b1v, acc[0][1], 0, 0, 0);
        acc[1][0] = __builtin_amdgcn_mfma_f32_16x16x32_bf16(a1, b0v, acc[1][0], 0, 0, 0);
        acc[1][1] = __builtin_amdgcn_mfma_f32_16x16x32_bf16(a1, b1v, acc[1][1], 0, 0, 0);
    }
    #pragma unroll
    for (int mi = 0; mi < 2; ++mi)
    #pragma unroll
    for (int ni = 0; ni < 2; ++ni)
    #pragma unroll
    for (int r = 0; r < 4; ++r) {
        int gm = m0 + mh * 32 + mi * 16 + (lane >> 4) * 4 + r;
        int gn = n0 + nh * 32 + ni * 16 + (lane & 15);
        float val = acc[mi][ni][r];
        if (MODE == 0) {
            if (gn < 512)      q [((gn >> 6) * S + gm) * DH + (gn & 63)] = val;
            else if (gn < 640) kk[(((gn - 512) >> 6) * S + gm) * DH + ((gn - 512) & 63)] = val;
            else               vv[(((gn - 640) >> 6) * S + gm) * DH + ((gn - 640) & 63)] = val;
        } else if (MODE == 1) {
            float h = val + bias[gn]; if (h < 0.f) h = 0.f;
            hid[(size_t)gm * N + gn] = f2bf(h);
        } else {
            outC[(size_t)gm * N + gn] = val;
        }
    }
}

// ---------------- kb/vb builder ----------------
__global__ void k_build_kbvb(const float* __restrict__ kbuf, const float* __restrict__ vbuf,
                             const float* __restrict__ k_pos, const float* __restrict__ v_pos,
                             unsigned short* __restrict__ kbvb) {
    int idx = blockIdx.x * 256 + threadIdx.x;   // 256*2048
    int r = idx >> 11, c = idx & 2047;
    int tt = c >> 6, dh = c & 63;
    int path = r >> 7, kh = (r >> 6) & 1, nc = r & 63;
    const float* src = path ? vbuf : kbuf;
    const float* pos = path ? v_pos : k_pos;
    float val = src[((kh * S) + nc * 32 + tt) * DH + dh] + pos[(kh * CBS + tt) * DH + dh];
    kbvb[idx] = f2bf(val);
}

// ---------------- mem_kv -> ck/cv row 0 ----------------
__global__ void k_mem_init(const float* __restrict__ mem_kv, float* __restrict__ ck, float* __restrict__ cv) {
    int t = threadIdx.x;
    int path = t >> 7, kh = (t >> 6) & 1, d = t & 63;
    float* dst = path ? cv : ck;
    dst[kh * 65 * 64 + d] = mem_kv[path * (KH * DH) + kh * DH + d];
}

// ---------------- MLP second layer ----------------
__global__ __launch_bounds__(256) void k_mlp2(const unsigned short* __restrict__ hid,
    const float* __restrict__ kc_w2, const float* __restrict__ kc_b2,
    const float* __restrict__ vc_w2, const float* __restrict__ vc_b2,
    float* __restrict__ ck, float* __restrict__ cv)
{
    int r = blockIdx.x, t = threadIdx.x;
    int path = r >> 7, kh = (r >> 6) & 1, nc = r & 63;
    const float* Wm = path ? vc_w2 : kc_w2;
    const float* b2 = path ? vc_b2 : kc_b2;
    int col = t & 63, part = t >> 6;
    const unsigned short* hrow = hid + (size_t)r * CDIM;
    float acc = 0.f;
    for (int k = part * 512; k < part * 512 + 512; ++k)
        acc += bf2f(hrow[k]) * Wm[k * 64 + col];
    __shared__ float red[4][64];
    red[part][col] = acc;
    __syncthreads();
    if (t < 64) {
        float sum = red[0][t] + red[1][t] + red[2][t] + red[3][t] + b2[t];
        float* dst = path ? cv : ck;
        dst[(kh * 65 + 1 + nc) * 64 + t] = sum;
    }
}

// ---------------- RoPE tables ----------------
__global__ void k_rope_table(float* __restrict__ ct, float* __restrict__ st) {
    int idx = blockIdx.x * 256 + threadIdx.x;   // 2048*32
    int s = idx >> 5, p = idx & 31;
    float inv = powf(10000.0f, -(float)p / 32.0f);
    float fr = (float)s * inv;
    ct[idx] = cosf(fr); st[idx] = sinf(fr);
}

// ---------------- fused rope(q), rope(k), convert(v) -> bf16 ----------------
__global__ __launch_bounds__(256) void k_ropeprep(
    const float* __restrict__ qb, const float* __restrict__ kbuf, const float* __restrict__ vbuf,
    const float* __restrict__ ct, const float* __restrict__ st,
    unsigned short* __restrict__ qr16, unsigned short* __restrict__ kr16,
    unsigned short* __restrict__ v16)
{
    int idx = blockIdx.x * 256 + threadIdx.x;   // (H*S + 2*KH*S) * 32
    int row = idx >> 5, p = idx & 31;
    const int QR = H * S, KR = KH * S;
    const float* src; unsigned short* dst; bool dorope;
    if (row < QR)           { src = qb   + (size_t)row * 64;             dst = qr16 + (size_t)row * 64;             dorope = true; }
    else if (row < QR + KR) { src = kbuf + (size_t)(row - QR) * 64;      dst = kr16 + (size_t)(row - QR) * 64;      dorope = true; }
    else                    { src = vbuf + (size_t)(row - QR - KR) * 64; dst = v16  + (size_t)(row - QR - KR) * 64; dorope = false; }
    float x0 = src[2 * p], x1 = src[2 * p + 1];
    if (dorope) {
        int s = row & (S - 1);
        float c = ct[s * 32 + p], sn = st[s * 32 + p];
        float y0 = x0 * c - x1 * sn, y1 = x1 * c + x0 * sn;
        dst[2 * p] = f2bf(y0); dst[2 * p + 1] = f2bf(y1);
    } else {
        dst[2 * p] = f2bf(x0); dst[2 * p + 1] = f2bf(x1);
    }
}

// ---------------- compressed attention + importance + top-8 ----------------
__global__ __launch_bounds__(256) void k_cattn(
    const float* __restrict__ q, const float* __restrict__ ck, const float* __restrict__ cv,
    float* __restrict__ c_out, int* __restrict__ sel)
{
    int kh = blockIdx.x >> 8, sc = blockIdx.x & 255;   // grid = 2*256
    int s_base = sc * 8;
    __shared__ float ckT[64][65];   // [d][j]
    __shared__ float cvL[64][66];   // [j][d]
    __shared__ float qL[4][64];
    __shared__ float simL[4][64];
    int t = threadIdx.x;
    for (int idx = t; idx < 4096; idx += 256) {
        int j = idx >> 6, d = idx & 63;
        ckT[d][j] = ck[(kh * 65 + j) * 64 + d];
        cvL[j][d] = cv[(kh * 65 + j) * 64 + d];
    }
    int g = t >> 6, lane = t & 63;
    for (int si = 0; si < 8; ++si) {
        int s = s_base + si;
        __syncthreads();
        qL[g][lane] = q[((kh * G + g) * S + s) * DH + lane];
        __syncthreads();
        int j = lane;
        bool valid = (j == 0) || (s >= j * 32);
        float sim = 0.f;
        #pragma unroll 8
        for (int d = 0; d < 64; ++d) sim += qL[g][d] * ckT[d][j];
        sim *= 0.125f;
        float simm = valid ? sim : -INFINITY;
        simL[g][j] = simm;
        float m = simm;
        for (int off = 32; off; off >>= 1) m = fmaxf(m, __shfl_xor(m, off));
        float p = valid ? __expf(simm - m) : 0.f;
        float den = p;
        for (int off = 32; off; off >>= 1) den += __shfl_xor(den, off);
        float pn = p / den;
        float acc = 0.f;
        #pragma unroll 8
        for (int jj = 0; jj < 64; ++jj)
            acc += __shfl(pn, jj) * cvL[jj][lane];
        c_out[((kh * G + g) * S + s) * DH + lane] = acc;
        __syncthreads();
        if (g == 0) {
            int l = lane;
            float lv = -INFINITY;
            if (l < 63 && s >= (l + 1) * 32)
                lv = 0.25f * (simL[0][l + 1] + simL[1][l + 1] + simL[2][l + 1] + simL[3][l + 1]);
            float mm = lv;
            for (int off = 32; off; off >>= 1) mm = fmaxf(mm, __shfl_xor(mm, off));
            mm = fmaxf(mm, -1000.0f);
            float e = (lv == -INFINITY) ? 0.f : __expf(lv - mm);
            float dd = e;
            for (int off = 32; off; off >>= 1) dd += __shfl_xor(dd, off);
            dd += __expf(-1000.0f - mm);
            float val = e / dd;
            float vc = val;
            int base = (kh * S + s) * 9;
            for (int t8 = 0; t8 < 8; ++t8) {
                float bv2 = vc; int bi = l;
                for (int off = 32; off; off >>= 1) {
                    float ov = __shfl_xor(bv2, off); int oi = __shfl_xor(bi, off);
                    if (ov > bv2 || (ov == bv2 && oi < bi)) { bv2 = ov; bi = oi; }
                }
                if (l == 0) sel[base + t8] = (bv2 > 1e-10f) ? bi : -1;
                if (l == bi) vc = -1.f;
            }
            if (l == 0) sel[base + 8] = s >> 5;
        }
    }
}

// ---------------- fine + sliding attention (merged, vectorized bf16 SIMT) ----
// blockIdx.y==0: fine (selected blocks);  ==1: sliding window.
// Sliding covers keys [max(0,s-128), s-1] with FULL unmasked 64-key chunks
// (2 for s>=128) plus an inline ~25-op diagonal update for key s — this
// removes the 3rd nearly-empty chunk iteration (1 valid key of 64).
// launch_bounds(256,4): VGPR cap 128 — a cap of 32 caused scratch spills.
__global__ __launch_bounds__(256, 4) void k_swattn(
    const unsigned short* __restrict__ qr16, const unsigned short* __restrict__ kr16,
    const unsigned short* __restrict__ v16, const int* __restrict__ sel,
    float* __restrict__ fob, float* __restrict__ sob)
{
    int kh = blockIdx.x >> 11, s = blockIdx.x & 2047;
    bool fine = (blockIdx.y == 0);
    float* outp = fine ? fob : sob;
    int t = threadIdx.x, w = t >> 6, lane = t & 63, g = w;
    __shared__ __align__(16) unsigned char KL[64 * 128];   // swizzled [key][grp^(key&7)]
    __shared__ __align__(16) unsigned char VL[64 * 144];   // [key][72 bf16]
    __shared__ unsigned short qL16[4][64];                  // wave-private
    __shared__ float pL[4][64];                             // wave-private

    qL16[g][lane] = qr16[(((size_t)kh * G + g) * S + s) * DH + lane];

    int own_t = s & 31;
    int base = (kh * S + s) * 9;
    float m_run = -INFINITY, l_run = 0.f;
    float acc0 = 0.f, acc1 = 0.f;
    int h = lane >> 5, dhalf = lane & 31;

    int lo = s - WIN; if (lo < 0) lo = 0;
    int nch = fine ? 5 : ((s - lo + 63) >> 6);   // sliding: full chunks over [lo, s-1]

    for (int c = 0; c < nch; ++c) {
        int bA = 0, bB = 0, kb = 0;
        bool vA, vB;
        if (fine) {
            bA = sel[base + c * 2];
            bB = (c < 4) ? sel[base + c * 2 + 1] : -1;
            if (bA < 0 && bB < 0) continue;   // uniform across block
            vA = bA >= 0; vB = bB >= 0;
        } else {
            kb = lo + c * 64; vA = true; vB = true;
        }
        __syncthreads();
        // ---- stage K (swizzled) and V (row-major), zero-fill invalid ----
        {
            int key = w * 16 + (lane & 15);
            int gkey; bool kv;
            if (fine) {
                int b = (key < 32) ? bA : bB;
                kv = b >= 0;
                gkey = (b < 0 ? 0 : b) * 32 + (key & 31);
            } else {
                gkey = kb + key;
                kv = gkey < s;            // key s handled by diagonal path
            }
            const uint4* kp = (const uint4*)&kr16[((size_t)kh * S + gkey) * DH];
            const uint4* vp = (const uint4*)&v16 [((size_t)kh * S + gkey) * DH];
            uint4 z = make_uint4(0, 0, 0, 0);
            #pragma unroll
            for (int i = 0; i < 2; ++i) {
                int grp = (lane >> 4) + 4 * i;
                uint4 kd = kv ? kp[grp] : z;
                uint4 vd = kv ? vp[grp] : z;
                *(uint4*)(KL + key * 128 + 16 * (grp ^ (key & 7))) = kd;
                *(uint4*)(VL + key * 144 + 16 * grp) = vd;
            }
        }
        __syncthreads();
        // ---- QK^T: lane = key j ----
        int j = lane;
        bool valid;
        if (fine) {
            valid = (j < 32) ? vA : vB;
            if (c == 4) valid = valid && (j < 32) && (j <= own_t);
        } else {
            valid = (kb + j) < s;
        }
        float sv = 0.f;
        #pragma unroll
        for (int grp = 0; grp < 8; ++grp) {
            uint4 kk = *(const uint4*)(KL + j * 128 + 16 * (grp ^ (j & 7)));
            uint4 qq = *(const uint4*)((const unsigned char*)qL16 + g * 128 + 16 * grp);
            sv += bflo(qq.x) * bflo(kk.x) + bfhi(qq.x) * bfhi(kk.x);
            sv += bflo(qq.y) * bflo(kk.y) + bfhi(qq.y) * bfhi(kk.y);
            sv += bflo(qq.z) * bflo(kk.z) + bfhi(qq.z) * bfhi(kk.z);
            sv += bflo(qq.w) * bflo(kk.w) + bfhi(qq.w) * bfhi(kk.w);
        }
        float sim = valid ? sv * 0.125f : -INFINITY;
        float cm = sim;
        for (int off = 32; off; off >>= 1) cm = fmaxf(cm, __shfl_xor(cm, off));
        float nm = fmaxf(m_run, cm);
        float alpha = __expf(m_run - nm);
        float p = valid ? __expf(sim - nm) : 0.f;
        float ps = p;
        for (int off = 32; off; off >>= 1) ps += __shfl_xor(ps, off);
        l_run = l_run * alpha + ps;
        pL[g][j] = p;                 // wave-private: no barrier needed
        m_run = nm;
        acc0 *= alpha; acc1 *= alpha;
        // ---- PV: lane owns dims (2*dhalf, 2*dhalf+1), key-half h ----
        bool hv = (h == 0) ? vA : vB;
        if (hv) {
            #pragma unroll
            for (int j4 = 0; j4 < 8; ++j4) {
                float4 p4 = *(const float4*)&pL[g][h * 32 + j4 * 4];
                const float* pp = (const float*)&p4;
                #pragma unroll
                for (int qq = 0; qq < 4; ++qq) {
                    unsigned int v2 = *(const unsigned int*)(VL + (h * 32 + j4 * 4 + qq) * 144 + 4 * dhalf);
                    acc0 += pp[qq] * bflo(v2);
                    acc1 += pp[qq] * bfhi(v2);
                }
            }
        }
    }
    if (!fine) {
        // ---- diagonal key s: single online-softmax step ----
        float pr = bf2f(qL16[g][lane]) * bf2f(kr16[((size_t)kh * S + s) * DH + lane]);
        for (int off = 32; off; off >>= 1) pr += __shfl_xor(pr, off);
        float sim = pr * 0.125f;
        float nm = fmaxf(m_run, sim);
        float alpha = __expf(m_run - nm);
        float p = __expf(sim - nm);
        l_run = l_run * alpha + p;
        acc0 *= alpha; acc1 *= alpha;
        if (h == 0) {
            unsigned int v2 = *(const unsigned int*)&v16[(((size_t)kh * S + s) * DH) + 2 * dhalf];
            acc0 += p * bflo(v2);
            acc1 += p * bfhi(v2);
        }
        m_run = nm;
    }
    acc0 += __shfl_xor(acc0, 32);
    acc1 += __shfl_xor(acc1, 32);
    if (lane < 32) {
        float inv = 1.f / l_run;
        float2 o2 = make_float2(acc0 * inv, acc1 * inv);
        *(float2*)&outp[(((size_t)kh * G + g) * S + s) * DH + 2 * dhalf] = o2;
    }
}

// ---------------- gates + combine -> bf16 ----------------
__global__ __launch_bounds__(256) void k_combine(
    const unsigned short* __restrict__ xbf, const float* __restrict__ comb_w, const float* __restrict__ comb_b,
    const float* __restrict__ c_out, const float* __restrict__ f_out, const float* __restrict__ s_out,
    unsigned short* __restrict__ comb)
{
    int s = blockIdx.x, t = threadIdx.x;
    __shared__ float gpart[24][8];
    __shared__ float gates[24];
    if (t < 192) {
        int cc = t >> 3, pt = t & 7;
        float sum = 0.f;
        for (int d = pt * 64; d < pt * 64 + 64; ++d)
            sum += bf2f(xbf[s * D + d]) * comb_w[d * 24 + cc];
        gpart[cc][pt] = sum;
    }
    __syncthreads();
    if (t < 24) {
        float sum = comb_b[t];
        for (int i = 0; i < 8; ++i) sum += gpart[t][i];
        gates[t] = 1.f / (1.f + __expf(-sum));
    }
    __syncthreads();
    for (int o = t; o < 512; o += 256) {
        int h = o >> 6, d = o & 63;
        int idx = (h * S + s) * DH + d;
        float r = gates[h * 3] * c_out[idx] + gates[h * 3 + 1] * f_out[idx] + gates[h * 3 + 2] * s_out[idx];
        comb[s * D + o] = f2bf(r);
    }
}

extern "C" void kernel_launch(void* const* d_in, const int* in_sizes, int n_in,
                              void* d_out, int out_size, void* d_ws, size_t ws_size,
                              hipStream_t stream)
{
    (void)in_sizes; (void)n_in; (void)out_size; (void)ws_size;
    const float* inp    = (const float*)d_in[0];
    const float* norm_w = (const float*)d_in[1];
    const float* w_qkv  = (const float*)d_in[2];
    const float* mem_kv = (const float*)d_in[3];
    const float* k_pos  = (const float*)d_in[4];
    const float* v_pos  = (const float*)d_in[5];
    const float* kc_w1  = (const float*)d_in[6];
    const float* kc_b1  = (const float*)d_in[7];
    const float* kc_w2  = (const float*)d_in[8];
    const float* kc_b2  = (const float*)d_in[9];
    const float* vc_w1  = (const float*)d_in[10];
    const float* vc_b1  = (const float*)d_in[11];
    const float* vc_w2  = (const float*)d_in[12];
    const float* vc_b2  = (const float*)d_in[13];
    const float* comb_w = (const float*)d_in[14];
    const float* comb_b = (const float*)d_in[15];
    const float* out_w  = (const float*)d_in[16];
    float* out = (float*)d_out;

    char* w = (char*)d_ws;
    size_t off = 0;
    auto alloc = [&](size_t bytes) { void* p = w + off; off += (bytes + 255) & ~(size_t)255; return p; };
    unsigned short* xbf   = (unsigned short*)alloc((size_t)S * D * 2);
    unsigned short* kbvb  = (unsigned short*)alloc((size_t)256 * 2048 * 2);
    unsigned short* hid   = (unsigned short*)alloc((size_t)256 * 2048 * 2);
    unsigned short* combb = (unsigned short*)alloc((size_t)S * 512 * 2);
    unsigned short* qr16  = (unsigned short*)alloc((size_t)H * S * DH * 2);
    unsigned short* kr16  = (unsigned short*)alloc((size_t)KH * S * DH * 2);
    unsigned short* v16   = (unsigned short*)alloc((size_t)KH * S * DH * 2);
    float* qb   = (float*)alloc((size_t)H * S * DH * 4);
    float* kbuf = (float*)alloc((size_t)KH * S * DH * 4);
    float* vbuf = (float*)alloc((size_t)KH * S * DH * 4);
    float* ckb  = (float*)alloc((size_t)KH * 65 * 64 * 4);
    float* cvb  = (float*)alloc((size_t)KH * 65 * 64 * 4);
    float* cob  = (float*)alloc((size_t)H * S * DH * 4);
    float* fob  = (float*)alloc((size_t)H * S * DH * 4);
    float* sob  = (float*)alloc((size_t)H * S * DH * 4);
    float* ctab = (float*)alloc((size_t)S * 32 * 4);
    float* stab = (float*)alloc((size_t)S * 32 * 4);
    int*   selb = (int*)alloc((size_t)KH * S * 9 * 4);

    // RMSNorm
    k_rmsnorm<<<S, 256, 0, stream>>>(inp, norm_w, xbf);

    // QKV projection (B = f32 weights, converted during staging)
    k_gemm<0><<<dim3(768 / 64, S / 64), 256, 0, stream>>>(
        xbf, w_qkv, nullptr, nullptr, nullptr, S, 768, 512,
        qb, kbuf, vbuf, nullptr, nullptr);

    // compress MLP layer 1
    k_build_kbvb<<<(256 * 2048) / 256, 256, 0, stream>>>(kbuf, vbuf, k_pos, v_pos, kbvb);
    k_gemm<1><<<dim3(2048 / 64, 256 / 64), 256, 0, stream>>>(
        kbvb, kc_w1, vc_w1, kc_b1, vc_b1, 256, 2048, 2048,
        nullptr, nullptr, nullptr, hid, nullptr);

    // compress MLP layer 2 + mem row
    k_mem_init<<<1, 256, 0, stream>>>(mem_kv, ckb, cvb);
    k_mlp2<<<256, 256, 0, stream>>>(hid, kc_w2, kc_b2, vc_w2, vc_b2, ckb, cvb);

    // RoPE tables + fused rope(q)/rope(k)/convert(v)
    k_rope_table<<<(S * 32) / 256, 256, 0, stream>>>(ctab, stab);
    k_ropeprep<<<((H + 2 * KH) * S * 32) / 256, 256, 0, stream>>>(
        qb, kbuf, vbuf, ctab, stab, qr16, kr16, v16);

    // compressed attention + importance + top-8 selection
    k_cattn<<<KH * 256, 256, 0, stream>>>(qb, ckb, cvb, cob, selb);

    // fine + sliding attention (merged dispatch)
    k_swattn<<<dim3(KH * S, 2), 256, 0, stream>>>(qr16, kr16, v16, selb, fob, sob);

    // gated combine + output projection
    k_combine<<<S, 256, 0, stream>>>(xbf, comb_w, comb_b, cob, fob, sob, combb);
    k_gemm<2><<<dim3(512 / 64, S / 64), 256, 0, stream>>>(
        combb, out_w, nullptr, nullptr, nullptr, S, 512, 512,
        nullptr, nullptr, nullptr, nullptr, out);
}